// Round 6
// baseline (996.838 us; speedup 1.0000x reference)
//
#include <hip/hip_runtime.h>
#include <hip/hip_bf16.h>
#include <hip/hip_fp16.h>

// GCN forward. fp16 storage for inter-layer tensors; fp32 accum everywhere
// (gather accum, MFMA accum, BN stats, residual, readout).
// R1: gcnt via binary search (was 285us atomic histogram).
// R2: fp16 gather operand.
// R3: v_mfma_f32_16x16x32_f16 GEMM; W pre-swizzled to B-frag layout.
// R4: CSR build: LDS-histogram deg_out; rank-from-atomic kills fill cursor.
// R5: gather fused into GEMM (gather -> registers -> fp16 -> LDS A-tile ->
//     MFMA, no P1h round-trip); hl stored fp16; embed GEMM stages fp32->fp16
//     directly (h2h_k dropped).

#define N_NODES 100000
#define N_EDGES 1600000
#define N_GRAPHS 128
#define DIM 128
#define N_LAYERS 4
#define BN_EPS 1e-5f
#define SCAN_NB 98  // ceil(N_NODES / 1024)

typedef __attribute__((ext_vector_type(8))) _Float16 half8;
typedef __attribute__((ext_vector_type(4))) float floatx4;

// ---------------- deg_out: range-partitioned LDS histogram ----------------
__global__ __launch_bounds__(256) void histsrc_k(const int* __restrict__ src,
                                                 int* __restrict__ deg_out) {
  __shared__ unsigned sbin[16384];
  int range = blockIdx.x >> 6;  // 0..3
  int chunk = blockIdx.x & 63;  // 0..63
  int base = range << 15;       // *32768
  for (int i = threadIdx.x; i < 16384; i += 256) sbin[i] = 0;
  __syncthreads();
  int e0 = chunk * 25000;
  int e1 = e0 + 25000;  // 64*25000 == N_EDGES exactly
  for (int e = e0 + threadIdx.x; e < e1; e += 256) {
    int s = src[e] - base;
    if ((unsigned)s < 32768u)
      atomicAdd(&sbin[s >> 1], (s & 1) ? 0x10000u : 1u);
  }
  __syncthreads();
  for (int i = threadIdx.x; i < 16384; i += 256) {
    unsigned w = sbin[i];
    if (w) {
      unsigned lo = w & 0xffffu, hi = w >> 16;
      int n0 = base + 2 * i;
      if (lo && n0 < N_NODES) atomicAdd(&deg_out[n0], (int)lo);
      if (hi && n0 + 1 < N_NODES) atomicAdd(&deg_out[n0 + 1], (int)hi);
    }
  }
}

// ---------------- deg_in + per-edge rank (atomic return value) -------------
__global__ __launch_bounds__(256) void rankdeg_k(const int* __restrict__ dst,
                                                 int* deg_in,
                                                 int* __restrict__ rank) {
  int e = blockIdx.x * 256 + threadIdx.x;
  if (e < N_EDGES) rank[e] = atomicAdd(&deg_in[dst[e]], 1);
}

__global__ __launch_bounds__(256) void norm_k(const int* __restrict__ deg_out,
                                              const int* __restrict__ deg_in,
                                              float* __restrict__ norm_src,
                                              float* __restrict__ norm_dst) {
  int i = blockIdx.x * 256 + threadIdx.x;
  if (i < N_NODES) {
    int dso = deg_out[i] > 1 ? deg_out[i] : 1;
    int dsi = deg_in[i] > 1 ? deg_in[i] : 1;
    norm_src[i] = rsqrtf((float)dso);
    norm_dst[i] = rsqrtf((float)dsi);
  }
}

// ---------------- exclusive scan of deg_in -> row_start ----------------
__global__ __launch_bounds__(256) void scan1_k(const int* __restrict__ deg,
                                               int* __restrict__ bsums) {
  __shared__ int sred[256];
  int t = threadIdx.x;
  int i0 = blockIdx.x * 1024 + t * 4;
  int s = 0;
#pragma unroll
  for (int j = 0; j < 4; ++j) {
    int i = i0 + j;
    s += (i < N_NODES) ? deg[i] : 0;
  }
  sred[t] = s;
  __syncthreads();
  for (int off = 128; off > 0; off >>= 1) {
    if (t < off) sred[t] += sred[t + off];
    __syncthreads();
  }
  if (t == 0) bsums[blockIdx.x] = sred[0];
}

__global__ __launch_bounds__(128) void scan2_k(int* __restrict__ bsums,
                                               int* __restrict__ row_start) {
  __shared__ int sd[128];
  int t = threadIdx.x;
  int v = (t < SCAN_NB) ? bsums[t] : 0;
  sd[t] = v;
  __syncthreads();
  for (int off = 1; off < 128; off <<= 1) {
    int tmp = (t >= off) ? sd[t - off] : 0;
    __syncthreads();
    sd[t] += tmp;
    __syncthreads();
  }
  if (t < SCAN_NB) bsums[t] = sd[t] - v;  // exclusive
  if (t == 0) row_start[N_NODES] = N_EDGES;
}

__global__ __launch_bounds__(256) void scan3_k(const int* __restrict__ deg,
                                               const int* __restrict__ bsums,
                                               int* __restrict__ row_start) {
  __shared__ int sd[256];
  int t = threadIdx.x;
  int i0 = blockIdx.x * 1024 + t * 4;
  int d[4];
  int tot = 0;
#pragma unroll
  for (int j = 0; j < 4; ++j) {
    int i = i0 + j;
    d[j] = (i < N_NODES) ? deg[i] : 0;
    tot += d[j];
  }
  sd[t] = tot;
  __syncthreads();
  for (int off = 1; off < 256; off <<= 1) {
    int tmp = (t >= off) ? sd[t - off] : 0;
    __syncthreads();
    sd[t] += tmp;
    __syncthreads();
  }
  int run = bsums[blockIdx.x] + sd[t] - tot;
#pragma unroll
  for (int j = 0; j < 4; ++j) {
    int i = i0 + j;
    if (i < N_NODES) row_start[i] = run;
    run += d[j];
  }
}

// ---------------- CSR fill, atomic-free (slot = row_start + rank) ----------
__global__ __launch_bounds__(256) void fill2_k(const int* __restrict__ src,
                                               const int* __restrict__ dst,
                                               const int* __restrict__ rank,
                                               const int* __restrict__ row_start,
                                               int* __restrict__ csr_src) {
  int e = blockIdx.x * 256 + threadIdx.x;
  if (e < N_EDGES) csr_src[row_start[dst[e]] + rank[e]] = src[e];
}

// ---------------- W pre-swizzle to B-fragment layout ----------------
// Bsw[mat][ct][ks][lane][j] = fp16( W[mat][ k=ks*32+(lane>>4)*8+j ][ n=ct*16+(lane&15) ] )
__global__ __launch_bounds__(256) void wswz_k(const float* __restrict__ W,
                                              __half* __restrict__ Bsw) {
  int w = blockIdx.x >> 3, ct = blockIdx.x & 7;
  int ks = threadIdx.x >> 6, lane = threadIdx.x & 63;
  int n = ct * 16 + (lane & 15);
  int k0 = ks * 32 + (lane >> 4) * 8;
  const float* Wm = W + (size_t)w * 16384;
  __half* o = Bsw + ((((size_t)w * 8 + ct) * 4 + ks) * 64 + lane) * 8;
#pragma unroll
  for (int j = 0; j < 8; ++j) o[j] = __float2half(Wm[(k0 + j) * 128 + n]);
}

// ---------------- shared MFMA core (A-tile already in sA) ----------------
// 256 thr = 4 waves; 128 rows x 128 cols; K=128 in four 32-chunks.
// Returns acc[2][8]; C layout: row = tr*16 + quad*4 + reg, col = ct*16+lrow.
__device__ inline void mfma_core(const __half* sA, const __half* __restrict__ Bsw,
                                 floatx4 (&acc)[2][8], int w, int lane,
                                 int quad, int lrow) {
#pragma unroll
  for (int tr = 0; tr < 2; ++tr)
#pragma unroll
    for (int ct = 0; ct < 8; ++ct) acc[tr][ct] = (floatx4)(0.f);
#pragma unroll
  for (int ks = 0; ks < 4; ++ks) {
    half8 afrag[2];
#pragma unroll
    for (int tr = 0; tr < 2; ++tr) {
      int m = w * 32 + tr * 16 + lrow;
      afrag[tr] = *(const half8*)(&sA[m * 136 + ks * 32 + quad * 8]);
    }
#pragma unroll
    for (int ct = 0; ct < 8; ++ct) {
      half8 bfrag = *(const half8*)(&Bsw[(((size_t)ct * 4 + ks) * 64 + lane) * 8]);
      acc[0][ct] = __builtin_amdgcn_mfma_f32_16x16x32_f16(afrag[0], bfrag,
                                                          acc[0][ct], 0, 0, 0);
      acc[1][ct] = __builtin_amdgcn_mfma_f32_16x16x32_f16(afrag[1], bfrag,
                                                          acc[1][ct], 0, 0, 0);
    }
  }
}

// ---------------- embed GEMM: A = fp32 h @ W + b ; P0h = fp16(A*norm_src) ---
__global__ __launch_bounds__(256) void mfma_gemm_f32in(
    const float* __restrict__ X32, const __half* __restrict__ Bsw,
    const float* __restrict__ bias, float* __restrict__ Yf,
    __half* __restrict__ S16, const float* __restrict__ norm_src) {
  __shared__ __half sA[128 * 136];
  const int tid = threadIdx.x;
  const int w = tid >> 6, lane = tid & 63;
  const int quad = lane >> 4, lrow = lane & 15;
  const int row_base = blockIdx.x * 128;

  // stage fp32 tile -> fp16 LDS (4096 float4 reads)
#pragma unroll
  for (int i = 0; i < 16; ++i) {
    int g = i * 256 + tid;
    int r = g >> 5, q = g & 31;  // row, float4-slot (32 per fp32 row)
    int row = row_base + r;
    float4 v = make_float4(0.f, 0.f, 0.f, 0.f);
    if (row < N_NODES) v = ((const float4*)X32)[(size_t)row * 32 + q];
    union { __half2 h[2]; float f[2]; } u;
    u.h[0] = __floats2half2_rn(v.x, v.y);
    u.h[1] = __floats2half2_rn(v.z, v.w);
    *(float2*)(&sA[r * 136 + q * 4]) = *(float2*)u.f;
  }
  __syncthreads();

  floatx4 acc[2][8];
  mfma_core(sA, Bsw, acc, w, lane, quad, lrow);

#pragma unroll
  for (int ct = 0; ct < 8; ++ct) {
    int col = ct * 16 + lrow;
    float b = bias[col];
#pragma unroll
    for (int tr = 0; tr < 2; ++tr)
#pragma unroll
      for (int reg = 0; reg < 4; ++reg) {
        int row = row_base + w * 32 + tr * 16 + quad * 4 + reg;
        if (row < N_NODES) {
          float y = acc[tr][ct][reg] + b;
          Yf[(size_t)row * 128 + col] = y;
          S16[(size_t)row * 128 + col] = __float2half(y * norm_src[row]);
        }
      }
  }
}

// ---------------- fused gather + GEMM (+BN stats) ----------------
// Per block: 128 nodes. Phase 1: 16 lanes/node gather fp16 rows of P0h by CSR,
// fp32 accum, *norm_dst, fp16 -> LDS A-tile. Phase 2: MFMA vs pre-swizzled W.
// Epilogue: +bias, hl fp16 store, BN stats (fp32) via shuffle+LDS+atomics.
__global__ __launch_bounds__(256) void gath_gemm(
    const float4* __restrict__ Hs, const int* __restrict__ row_start,
    const int* __restrict__ csr_src, const float* __restrict__ norm_dst,
    const __half* __restrict__ Bsw, const float* __restrict__ bias,
    __half* __restrict__ hl16, float* __restrict__ stats) {
  __shared__ __half sA[128 * 136];
  const int tid = threadIdx.x;
  const int w = tid >> 6, lane = tid & 63;
  const int quad = lane >> 4, lrow = lane & 15;
  const int glane = tid & 15;  // gather lane within 16-thread group
  const int row_base = blockIdx.x * 128;

  // gather phase: 16 node-slots in parallel, 8 sequential groups
#pragma unroll 1
  for (int it = 0; it < 8; ++it) {
    int r = it * 16 + (tid >> 4);
    int node = row_base + r;
    float a[8] = {0.f, 0.f, 0.f, 0.f, 0.f, 0.f, 0.f, 0.f};
    float nd = 0.f;
    if (node < N_NODES) {
      nd = norm_dst[node];
      int s0 = row_start[node], s1 = row_start[node + 1];
      for (int e = s0; e < s1; e += 16) {
        int cnt = s1 - e;
        if (cnt > 16) cnt = 16;
        int idx = (glane < cnt) ? csr_src[e + glane] : 0;
        int j = 0;
        for (; j + 2 <= cnt; j += 2) {
          int sa = __shfl(idx, j, 16);
          int sb = __shfl(idx, j + 1, 16);
          float4 va = Hs[(size_t)sa * 16 + glane];
          float4 vb = Hs[(size_t)sb * 16 + glane];
          const __half2* ha = (const __half2*)&va;
          const __half2* hb = (const __half2*)&vb;
#pragma unroll
          for (int q = 0; q < 4; ++q) {
            float2 fa = __half22float2(ha[q]);
            float2 fb = __half22float2(hb[q]);
            a[2 * q] += fa.x + fb.x;
            a[2 * q + 1] += fa.y + fb.y;
          }
        }
        if (j < cnt) {
          int sa = __shfl(idx, j, 16);
          float4 va = Hs[(size_t)sa * 16 + glane];
          const __half2* ha = (const __half2*)&va;
#pragma unroll
          for (int q = 0; q < 4; ++q) {
            float2 fa = __half22float2(ha[q]);
            a[2 * q] += fa.x;
            a[2 * q + 1] += fa.y;
          }
        }
      }
    }
    union { __half2 h[4]; float4 f; } u;
    u.h[0] = __floats2half2_rn(a[0] * nd, a[1] * nd);
    u.h[1] = __floats2half2_rn(a[2] * nd, a[3] * nd);
    u.h[2] = __floats2half2_rn(a[4] * nd, a[5] * nd);
    u.h[3] = __floats2half2_rn(a[6] * nd, a[7] * nd);
    *(float4*)(&sA[r * 136 + glane * 8]) = u.f;
  }
  __syncthreads();

  floatx4 acc[2][8];
  mfma_core(sA, Bsw, acc, w, lane, quad, lrow);

  float psum[8], pqsum[8];
#pragma unroll
  for (int ct = 0; ct < 8; ++ct) {
    int col = ct * 16 + lrow;
    float b = bias[col];
    psum[ct] = 0.f;
    pqsum[ct] = 0.f;
#pragma unroll
    for (int tr = 0; tr < 2; ++tr)
#pragma unroll
      for (int reg = 0; reg < 4; ++reg) {
        int row = row_base + w * 32 + tr * 16 + quad * 4 + reg;
        if (row < N_NODES) {
          float y = acc[tr][ct][reg] + b;
          hl16[(size_t)row * 128 + col] = __float2half(y);
          psum[ct] += y;
          pqsum[ct] += y * y;
        }
      }
  }

#pragma unroll
  for (int ct = 0; ct < 8; ++ct) {
    psum[ct] += __shfl_xor(psum[ct], 16, 64);
    psum[ct] += __shfl_xor(psum[ct], 32, 64);
    pqsum[ct] += __shfl_xor(pqsum[ct], 16, 64);
    pqsum[ct] += __shfl_xor(pqsum[ct], 32, 64);
  }
  __syncthreads();  // sA no longer needed
  float* sred = (float*)sA;  // [4 waves][128] sum | [4][128] sumsq
  if (quad == 0) {
#pragma unroll
    for (int ct = 0; ct < 8; ++ct) {
      sred[w * 128 + ct * 16 + lrow] = psum[ct];
      sred[512 + w * 128 + ct * 16 + lrow] = pqsum[ct];
    }
  }
  __syncthreads();
  if (tid < 128) {
    float s = sred[tid] + sred[128 + tid] + sred[256 + tid] + sred[384 + tid];
    float q = sred[512 + tid] + sred[640 + tid] + sred[768 + tid] +
              sred[896 + tid];
    atomicAdd(&stats[tid], s);
    atomicAdd(&stats[128 + tid], q);
  }
}

// ---------------- BN finalize ----------------
__global__ __launch_bounds__(128) void bn_fin_k(const float* __restrict__ stats,
                                                const float* __restrict__ gamma,
                                                const float* __restrict__ beta,
                                                float* __restrict__ sc_sh) {
  int c = threadIdx.x;
  const float invn = 1.0f / (float)N_NODES;
  float mean = stats[c] * invn;
  float var = stats[128 + c] * invn - mean * mean;
  var = fmaxf(var, 0.f);
  float sc = gamma[c] * rsqrtf(var + BN_EPS);
  sc_sh[c] = sc;
  sc_sh[128 + c] = beta[c] - mean * sc;
}

// ---------------- BN apply + ReLU + residual (+ fp16 scale for gather) -----
// one thread per 8 cols: reads hl fp16 (16B), A fp32 (2x16B).
__global__ __launch_bounds__(256) void bnrelu_k(
    const __half* __restrict__ hl16, float* __restrict__ A,
    __half* __restrict__ S, const float* __restrict__ sc_sh,
    const float* __restrict__ norm_src, int write_scaled) {
  int idx = blockIdx.x * 256 + threadIdx.x;  // < N_NODES*16
  int node = idx >> 4;
  int c8 = idx & 15;
  float4 hv4 = *(const float4*)(hl16 + (size_t)idx * 8);
  const __half2* hp = (const __half2*)&hv4;
  const float4* sv = (const float4*)sc_sh;
  float4 s0 = sv[c8 * 2], s1 = sv[c8 * 2 + 1];
  float4 b0 = sv[32 + c8 * 2], b1 = sv[32 + c8 * 2 + 1];
  float4* Ap = (float4*)(A + (size_t)idx * 8);
  float4 a0 = Ap[0], a1 = Ap[1];
  float2 f0 = __half22float2(hp[0]), f1 = __half22float2(hp[1]);
  float2 f2 = __half22float2(hp[2]), f3 = __half22float2(hp[3]);
  float4 v0, v1;
  v0.x = fmaxf(f0.x * s0.x + b0.x, 0.f) + a0.x;
  v0.y = fmaxf(f0.y * s0.y + b0.y, 0.f) + a0.y;
  v0.z = fmaxf(f1.x * s0.z + b0.z, 0.f) + a0.z;
  v0.w = fmaxf(f1.y * s0.w + b0.w, 0.f) + a0.w;
  v1.x = fmaxf(f2.x * s1.x + b1.x, 0.f) + a1.x;
  v1.y = fmaxf(f2.y * s1.y + b1.y, 0.f) + a1.y;
  v1.z = fmaxf(f3.x * s1.z + b1.z, 0.f) + a1.z;
  v1.w = fmaxf(f3.y * s1.w + b1.w, 0.f) + a1.w;
  Ap[0] = v0;
  Ap[1] = v1;
  if (write_scaled) {
    float n = norm_src[node];
    union { __half2 h[4]; float4 f; } u;
    u.h[0] = __floats2half2_rn(v0.x * n, v0.y * n);
    u.h[1] = __floats2half2_rn(v0.z * n, v0.w * n);
    u.h[2] = __floats2half2_rn(v1.x * n, v1.y * n);
    u.h[3] = __floats2half2_rn(v1.z * n, v1.w * n);
    *(float4*)(S + (size_t)idx * 8) = u.f;
  }
}

// ---------------- readout ----------------
__global__ __launch_bounds__(256) void gbounds_k(const int* __restrict__ gid,
                                                 int* __restrict__ gstart) {
  int g = threadIdx.x;  // 0..128
  if (g > N_GRAPHS) return;
  int lo = 0, hi = N_NODES;
  while (lo < hi) {
    int mid = (lo + hi) >> 1;
    if (gid[mid] < g) lo = mid + 1; else hi = mid;
  }
  gstart[g] = lo;
}

__global__ __launch_bounds__(128) void gsum_k(const float* __restrict__ A,
                                              const int* __restrict__ gid,
                                              float* gsum) {
  int c = threadIdx.x;
  int n0 = blockIdx.x * 128;
  int n1 = n0 + 128;
  if (n1 > N_NODES) n1 = N_NODES;
  int cur = gid[n0];
  float local = 0.f;
  for (int n = n0; n < n1; ++n) {
    int g = gid[n];  // sorted: few changes per block
    if (g != cur) {
      atomicAdd(&gsum[cur * 128 + c], local);
      local = 0.f;
      cur = g;
    }
    local += A[(size_t)n * 128 + c];
  }
  atomicAdd(&gsum[cur * 128 + c], local);
}

__global__ __launch_bounds__(128) void gout_k(const float* __restrict__ gsum,
                                              const int* __restrict__ gstart,
                                              float* __restrict__ out) {
  int g = blockIdx.x, c = threadIdx.x;
  float cnt = (float)(gstart[g + 1] - gstart[g]);
  if (cnt < 1.f) cnt = 1.f;
  out[g * 128 + c] = gsum[g * 128 + c] / cnt;
}

// ---------------- launch ----------------
extern "C" void kernel_launch(void* const* d_in, const int* in_sizes, int n_in,
                              void* d_out, int out_size, void* d_ws,
                              size_t ws_size, hipStream_t stream) {
  const float* h = (const float*)d_in[0];
  const int* src = (const int*)d_in[1];
  const int* dst = (const int*)d_in[2];
  const int* gid = (const int*)d_in[3];
  const float* W_embed = (const float*)d_in[4];
  const float* b_embed = (const float*)d_in[5];
  const float* W_layers = (const float*)d_in[6];
  const float* b_layers = (const float*)d_in[7];
  const float* gamma = (const float*)d_in[8];
  const float* beta = (const float*)d_in[9];
  float* out = (float*)d_out;
  (void)in_sizes; (void)n_in; (void)out_size; (void)ws_size;

  char* ws = (char*)d_ws;
  size_t o = 0;
  auto alloc = [&](size_t bytes) -> char* {
    char* p = ws + o;
    o = (o + bytes + 255) & ~(size_t)255;
    return p;
  };
  float* norm_src = (float*)alloc(N_NODES * 4);
  float* norm_dst = (float*)alloc(N_NODES * 4);
  int* deg_out = (int*)alloc(N_NODES * 4);
  int* deg_in = (int*)alloc(N_NODES * 4);  // adjacent to deg_out (one memset)
  int* row_start = (int*)alloc((N_NODES + 1) * 4);
  int* bsums = (int*)alloc(SCAN_NB * 4);
  int* csr_src = (int*)alloc((size_t)N_EDGES * 4);
  int* rank = (int*)alloc((size_t)N_EDGES * 4);
  float* stats4 = (float*)alloc(N_LAYERS * 256 * 4);  // per-layer sum|sumsq
  float* gsum = (float*)alloc(N_GRAPHS * 128 * 4);    // adjacent to stats4
  int* gstart = (int*)alloc((N_GRAPHS + 1) * 4);
  float* sc_sh = (float*)alloc(256 * 4);
  __half* Bsw = (__half*)alloc(5 * 16384 * 2);  // swizzled W: embed + 4 layers
  float* A = (float*)alloc((size_t)N_NODES * 128 * 4);     // residual h (fp32)
  __half* P0h = (__half*)alloc((size_t)N_NODES * 128 * 2); // h*norm_src (fp16)
  __half* H16 = (__half*)alloc((size_t)N_NODES * 128 * 2); // hl (fp16)

  // zero accumulators (deg_out+deg_in contiguous; stats4+gsum contiguous)
  hipMemsetAsync(deg_out, 0, 2 * 400128, stream);
  hipMemsetAsync(stats4, 0, 4096 + 65536, stream);

  histsrc_k<<<256, 256, 0, stream>>>(src, deg_out);
  rankdeg_k<<<(N_EDGES + 255) / 256, 256, 0, stream>>>(dst, deg_in, rank);
  norm_k<<<(N_NODES + 255) / 256, 256, 0, stream>>>(deg_out, deg_in, norm_src,
                                                    norm_dst);
  scan1_k<<<SCAN_NB, 256, 0, stream>>>(deg_in, bsums);
  scan2_k<<<1, 128, 0, stream>>>(bsums, row_start);
  scan3_k<<<SCAN_NB, 256, 0, stream>>>(deg_in, bsums, row_start);
  fill2_k<<<(N_EDGES + 255) / 256, 256, 0, stream>>>(src, dst, rank, row_start,
                                                     csr_src);

  wswz_k<<<8, 256, 0, stream>>>(W_embed, Bsw);
  wswz_k<<<32, 256, 0, stream>>>(W_layers, Bsw + 16384);

  // embed: A = h @ W_embed + b ; P0h = fp16(A * norm_src)
  mfma_gemm_f32in<<<(N_NODES + 127) / 128, 256, 0, stream>>>(
      h, Bsw, b_embed, A, P0h, norm_src);

  for (int l = 0; l < N_LAYERS; ++l) {
    gath_gemm<<<(N_NODES + 127) / 128, 256, 0, stream>>>(
        (const float4*)P0h, row_start, csr_src, norm_dst,
        Bsw + (size_t)(1 + l) * 16384, b_layers + l * DIM, H16,
        stats4 + l * 256);
    bn_fin_k<<<1, 128, 0, stream>>>(stats4 + l * 256, gamma + l * DIM,
                                    beta + l * DIM, sc_sh);
    bnrelu_k<<<(N_NODES * 16 + 255) / 256, 256, 0, stream>>>(
        H16, A, P0h, sc_sh, norm_src, (l < N_LAYERS - 1) ? 1 : 0);
  }

  gbounds_k<<<1, 256, 0, stream>>>(gid, gstart);
  gsum_k<<<(N_NODES + 127) / 128, 128, 0, stream>>>(A, gid, gsum);
  gout_k<<<N_GRAPHS, 128, 0, stream>>>(gsum, gstart, out);
}

// Round 7
// 908.189 us; speedup vs baseline: 1.0976x; 1.0976x over previous
//
#include <hip/hip_runtime.h>
#include <hip/hip_bf16.h>
#include <hip/hip_fp16.h>

// GCN forward. fp16 storage for inter-layer tensors; fp32 accum everywhere
// (gather accum, MFMA accum, BN stats, residual, readout).
// R1: gcnt via binary search (was 285us atomic histogram).
// R2: fp16 gather operand.
// R3: v_mfma_f32_16x16x32_f16 GEMM; W pre-swizzled to B-frag layout.
// R4: rank-from-atomic kills fill cursor atomic.
// R5: hl fp16; bnrelu fp16-input; embed GEMM stages fp32->fp16 directly.
// R6: REVERTED R5's gather+GEMM fusion (141us/layer @ 18% occupancy — the
//     latency-bound gather needs the 6250-block grid, not 782). Gather is
//     4-wide unrolled for MLP. histsrc LDS-histogram reverted too (flush
//     atomics ~= plain atomics); deg_out+deg_in+rank in one edge pass.

#define N_NODES 100000
#define N_EDGES 1600000
#define N_GRAPHS 128
#define DIM 128
#define N_LAYERS 4
#define BN_EPS 1e-5f
#define SCAN_NB 98  // ceil(N_NODES / 1024)

typedef __attribute__((ext_vector_type(8))) _Float16 half8;
typedef __attribute__((ext_vector_type(4))) float floatx4;

// ---------------- degrees + per-edge rank (one pass) ----------------
__global__ __launch_bounds__(256) void degrank_k(const int* __restrict__ src,
                                                 const int* __restrict__ dst,
                                                 int* deg_out, int* deg_in,
                                                 int* __restrict__ rank) {
  int e = blockIdx.x * 256 + threadIdx.x;
  if (e < N_EDGES) {
    atomicAdd(&deg_out[src[e]], 1);
    rank[e] = atomicAdd(&deg_in[dst[e]], 1);
  }
}

__global__ __launch_bounds__(256) void norm_k(const int* __restrict__ deg_out,
                                              const int* __restrict__ deg_in,
                                              float* __restrict__ norm_src,
                                              float* __restrict__ norm_dst) {
  int i = blockIdx.x * 256 + threadIdx.x;
  if (i < N_NODES) {
    int dso = deg_out[i] > 1 ? deg_out[i] : 1;
    int dsi = deg_in[i] > 1 ? deg_in[i] : 1;
    norm_src[i] = rsqrtf((float)dso);
    norm_dst[i] = rsqrtf((float)dsi);
  }
}

// ---------------- exclusive scan of deg_in -> row_start ----------------
__global__ __launch_bounds__(256) void scan1_k(const int* __restrict__ deg,
                                               int* __restrict__ bsums) {
  __shared__ int sred[256];
  int t = threadIdx.x;
  int i0 = blockIdx.x * 1024 + t * 4;
  int s = 0;
#pragma unroll
  for (int j = 0; j < 4; ++j) {
    int i = i0 + j;
    s += (i < N_NODES) ? deg[i] : 0;
  }
  sred[t] = s;
  __syncthreads();
  for (int off = 128; off > 0; off >>= 1) {
    if (t < off) sred[t] += sred[t + off];
    __syncthreads();
  }
  if (t == 0) bsums[blockIdx.x] = sred[0];
}

__global__ __launch_bounds__(128) void scan2_k(int* __restrict__ bsums,
                                               int* __restrict__ row_start) {
  __shared__ int sd[128];
  int t = threadIdx.x;
  int v = (t < SCAN_NB) ? bsums[t] : 0;
  sd[t] = v;
  __syncthreads();
  for (int off = 1; off < 128; off <<= 1) {
    int tmp = (t >= off) ? sd[t - off] : 0;
    __syncthreads();
    sd[t] += tmp;
    __syncthreads();
  }
  if (t < SCAN_NB) bsums[t] = sd[t] - v;  // exclusive
  if (t == 0) row_start[N_NODES] = N_EDGES;
}

__global__ __launch_bounds__(256) void scan3_k(const int* __restrict__ deg,
                                               const int* __restrict__ bsums,
                                               int* __restrict__ row_start) {
  __shared__ int sd[256];
  int t = threadIdx.x;
  int i0 = blockIdx.x * 1024 + t * 4;
  int d[4];
  int tot = 0;
#pragma unroll
  for (int j = 0; j < 4; ++j) {
    int i = i0 + j;
    d[j] = (i < N_NODES) ? deg[i] : 0;
    tot += d[j];
  }
  sd[t] = tot;
  __syncthreads();
  for (int off = 1; off < 256; off <<= 1) {
    int tmp = (t >= off) ? sd[t - off] : 0;
    __syncthreads();
    sd[t] += tmp;
    __syncthreads();
  }
  int run = bsums[blockIdx.x] + sd[t] - tot;
#pragma unroll
  for (int j = 0; j < 4; ++j) {
    int i = i0 + j;
    if (i < N_NODES) row_start[i] = run;
    run += d[j];
  }
}

// ---------------- CSR fill, atomic-free (slot = row_start + rank) ----------
__global__ __launch_bounds__(256) void fill2_k(const int* __restrict__ src,
                                               const int* __restrict__ dst,
                                               const int* __restrict__ rank,
                                               const int* __restrict__ row_start,
                                               int* __restrict__ csr_src) {
  int e = blockIdx.x * 256 + threadIdx.x;
  if (e < N_EDGES) csr_src[row_start[dst[e]] + rank[e]] = src[e];
}

// ---------------- W pre-swizzle to B-fragment layout ----------------
// Bsw[mat][ct][ks][lane][j] = fp16( W[mat][ k=ks*32+(lane>>4)*8+j ][ n=ct*16+(lane&15) ] )
__global__ __launch_bounds__(256) void wswz_k(const float* __restrict__ W,
                                              __half* __restrict__ Bsw) {
  int w = blockIdx.x >> 3, ct = blockIdx.x & 7;
  int ks = threadIdx.x >> 6, lane = threadIdx.x & 63;
  int n = ct * 16 + (lane & 15);
  int k0 = ks * 32 + (lane >> 4) * 8;
  const float* Wm = W + (size_t)w * 16384;
  __half* o = Bsw + ((((size_t)w * 8 + ct) * 4 + ks) * 64 + lane) * 8;
#pragma unroll
  for (int j = 0; j < 8; ++j) o[j] = __float2half(Wm[(k0 + j) * 128 + n]);
}

// ---------------- shared MFMA core (A-tile already in sA) ----------------
// 256 thr = 4 waves; 128 rows x 128 cols; K=128 in four 32-chunks.
// C layout: row = tr*16 + quad*4 + reg, col = ct*16 + lrow.
__device__ inline void mfma_core(const __half* sA, const __half* __restrict__ Bsw,
                                 floatx4 (&acc)[2][8], int w, int lane,
                                 int quad, int lrow) {
#pragma unroll
  for (int tr = 0; tr < 2; ++tr)
#pragma unroll
    for (int ct = 0; ct < 8; ++ct) acc[tr][ct] = (floatx4)(0.f);
#pragma unroll
  for (int ks = 0; ks < 4; ++ks) {
    half8 afrag[2];
#pragma unroll
    for (int tr = 0; tr < 2; ++tr) {
      int m = w * 32 + tr * 16 + lrow;
      afrag[tr] = *(const half8*)(&sA[m * 136 + ks * 32 + quad * 8]);
    }
#pragma unroll
    for (int ct = 0; ct < 8; ++ct) {
      half8 bfrag = *(const half8*)(&Bsw[(((size_t)ct * 4 + ks) * 64 + lane) * 8]);
      acc[0][ct] = __builtin_amdgcn_mfma_f32_16x16x32_f16(afrag[0], bfrag,
                                                          acc[0][ct], 0, 0, 0);
      acc[1][ct] = __builtin_amdgcn_mfma_f32_16x16x32_f16(afrag[1], bfrag,
                                                          acc[1][ct], 0, 0, 0);
    }
  }
}

// ---------------- embed GEMM: A = fp32 h @ W + b ; P0h = fp16(A*norm_src) ---
__global__ __launch_bounds__(256) void mfma_gemm_f32in(
    const float* __restrict__ X32, const __half* __restrict__ Bsw,
    const float* __restrict__ bias, float* __restrict__ Yf,
    __half* __restrict__ S16, const float* __restrict__ norm_src) {
  __shared__ __half sA[128 * 136];
  const int tid = threadIdx.x;
  const int w = tid >> 6, lane = tid & 63;
  const int quad = lane >> 4, lrow = lane & 15;
  const int row_base = blockIdx.x * 128;

  // stage fp32 tile -> fp16 LDS (4096 float4 reads)
#pragma unroll
  for (int i = 0; i < 16; ++i) {
    int g = i * 256 + tid;
    int r = g >> 5, q = g & 31;  // row, float4-slot (32 per fp32 row)
    int row = row_base + r;
    float4 v = make_float4(0.f, 0.f, 0.f, 0.f);
    if (row < N_NODES) v = ((const float4*)X32)[(size_t)row * 32 + q];
    union { __half2 h[2]; float f[2]; } u;
    u.h[0] = __floats2half2_rn(v.x, v.y);
    u.h[1] = __floats2half2_rn(v.z, v.w);
    *(float2*)(&sA[r * 136 + q * 4]) = *(float2*)u.f;
  }
  __syncthreads();

  floatx4 acc[2][8];
  mfma_core(sA, Bsw, acc, w, lane, quad, lrow);

#pragma unroll
  for (int ct = 0; ct < 8; ++ct) {
    int col = ct * 16 + lrow;
    float b = bias[col];
#pragma unroll
    for (int tr = 0; tr < 2; ++tr)
#pragma unroll
      for (int reg = 0; reg < 4; ++reg) {
        int row = row_base + w * 32 + tr * 16 + quad * 4 + reg;
        if (row < N_NODES) {
          float y = acc[tr][ct][reg] + b;
          Yf[(size_t)row * 128 + col] = y;
          S16[(size_t)row * 128 + col] = __float2half(y * norm_src[row]);
        }
      }
  }
}

// ---------------- layer GEMM: hl16 = fp16( agg16 @ W + b ), + BN stats ----
__global__ __launch_bounds__(256) void mfma_gemm_f16(
    const __half* __restrict__ X16, const __half* __restrict__ Bsw,
    const float* __restrict__ bias, __half* __restrict__ hl16,
    float* __restrict__ stats) {
  __shared__ __half sA[128 * 136];
  const int tid = threadIdx.x;
  const int w = tid >> 6, lane = tid & 63;
  const int quad = lane >> 4, lrow = lane & 15;
  const int row_base = blockIdx.x * 128;

  // stage fp16 tile (2048 float4 reads)
#pragma unroll
  for (int i = 0; i < 8; ++i) {
    int g = i * 256 + tid;
    int r = g >> 4, p = g & 15;
    int row = row_base + r;
    float4 v = make_float4(0.f, 0.f, 0.f, 0.f);
    if (row < N_NODES) v = ((const float4*)X16)[(size_t)row * 16 + p];
    *(float4*)(&sA[r * 136 + p * 8]) = v;
  }
  __syncthreads();

  floatx4 acc[2][8];
  mfma_core(sA, Bsw, acc, w, lane, quad, lrow);

  float psum[8], pqsum[8];
#pragma unroll
  for (int ct = 0; ct < 8; ++ct) {
    int col = ct * 16 + lrow;
    float b = bias[col];
    psum[ct] = 0.f;
    pqsum[ct] = 0.f;
#pragma unroll
    for (int tr = 0; tr < 2; ++tr)
#pragma unroll
      for (int reg = 0; reg < 4; ++reg) {
        int row = row_base + w * 32 + tr * 16 + quad * 4 + reg;
        if (row < N_NODES) {
          float y = acc[tr][ct][reg] + b;
          hl16[(size_t)row * 128 + col] = __float2half(y);
          psum[ct] += y;
          pqsum[ct] += y * y;
        }
      }
  }

#pragma unroll
  for (int ct = 0; ct < 8; ++ct) {
    psum[ct] += __shfl_xor(psum[ct], 16, 64);
    psum[ct] += __shfl_xor(psum[ct], 32, 64);
    pqsum[ct] += __shfl_xor(pqsum[ct], 16, 64);
    pqsum[ct] += __shfl_xor(pqsum[ct], 32, 64);
  }
  __syncthreads();  // sA no longer needed
  float* sred = (float*)sA;  // [4 waves][128] sum | [4][128] sumsq
  if (quad == 0) {
#pragma unroll
    for (int ct = 0; ct < 8; ++ct) {
      sred[w * 128 + ct * 16 + lrow] = psum[ct];
      sred[512 + w * 128 + ct * 16 + lrow] = pqsum[ct];
    }
  }
  __syncthreads();
  if (tid < 128) {
    float s = sred[tid] + sred[128 + tid] + sred[256 + tid] + sred[384 + tid];
    float q = sred[512 + tid] + sred[640 + tid] + sred[768 + tid] +
              sred[896 + tid];
    atomicAdd(&stats[tid], s);
    atomicAdd(&stats[128 + tid], q);
  }
}

// ---------------- BN finalize ----------------
__global__ __launch_bounds__(128) void bn_fin_k(const float* __restrict__ stats,
                                                const float* __restrict__ gamma,
                                                const float* __restrict__ beta,
                                                float* __restrict__ sc_sh) {
  int c = threadIdx.x;
  const float invn = 1.0f / (float)N_NODES;
  float mean = stats[c] * invn;
  float var = stats[128 + c] * invn - mean * mean;
  var = fmaxf(var, 0.f);
  float sc = gamma[c] * rsqrtf(var + BN_EPS);
  sc_sh[c] = sc;
  sc_sh[128 + c] = beta[c] - mean * sc;
}

// ---------------- BN apply + ReLU + residual (+ fp16 scale for gather) -----
__global__ __launch_bounds__(256) void bnrelu_k(
    const __half* __restrict__ hl16, float* __restrict__ A,
    __half* __restrict__ S, const float* __restrict__ sc_sh,
    const float* __restrict__ norm_src, int write_scaled) {
  int idx = blockIdx.x * 256 + threadIdx.x;  // < N_NODES*16
  int node = idx >> 4;
  int c8 = idx & 15;
  float4 hv4 = *(const float4*)(hl16 + (size_t)idx * 8);
  const __half2* hp = (const __half2*)&hv4;
  const float4* sv = (const float4*)sc_sh;
  float4 s0 = sv[c8 * 2], s1 = sv[c8 * 2 + 1];
  float4 b0 = sv[32 + c8 * 2], b1 = sv[32 + c8 * 2 + 1];
  float4* Ap = (float4*)(A + (size_t)idx * 8);
  float4 a0 = Ap[0], a1 = Ap[1];
  float2 f0 = __half22float2(hp[0]), f1 = __half22float2(hp[1]);
  float2 f2 = __half22float2(hp[2]), f3 = __half22float2(hp[3]);
  float4 v0, v1;
  v0.x = fmaxf(f0.x * s0.x + b0.x, 0.f) + a0.x;
  v0.y = fmaxf(f0.y * s0.y + b0.y, 0.f) + a0.y;
  v0.z = fmaxf(f1.x * s0.z + b0.z, 0.f) + a0.z;
  v0.w = fmaxf(f1.y * s0.w + b0.w, 0.f) + a0.w;
  v1.x = fmaxf(f2.x * s1.x + b1.x, 0.f) + a1.x;
  v1.y = fmaxf(f2.y * s1.y + b1.y, 0.f) + a1.y;
  v1.z = fmaxf(f3.x * s1.z + b1.z, 0.f) + a1.z;
  v1.w = fmaxf(f3.y * s1.w + b1.w, 0.f) + a1.w;
  Ap[0] = v0;
  Ap[1] = v1;
  if (write_scaled) {
    float n = norm_src[node];
    union { __half2 h[4]; float4 f; } u;
    u.h[0] = __floats2half2_rn(v0.x * n, v0.y * n);
    u.h[1] = __floats2half2_rn(v0.z * n, v0.w * n);
    u.h[2] = __floats2half2_rn(v1.x * n, v1.y * n);
    u.h[3] = __floats2half2_rn(v1.z * n, v1.w * n);
    *(float4*)(S + (size_t)idx * 8) = u.f;
  }
}

// ---------------- pull aggregation (fp16 in, fp16 out, fp32 accum) ---------
// 16 lanes/node, lane owns 8 cols (16B). 4-wide unrolled scattered loads.
__device__ inline void acc8(float (&a)[8], float4 v) {
  const __half2* hp = (const __half2*)&v;
#pragma unroll
  for (int q = 0; q < 4; ++q) {
    float2 f = __half22float2(hp[q]);
    a[2 * q] += f.x;
    a[2 * q + 1] += f.y;
  }
}

__global__ __launch_bounds__(256) void gather_k(
    const float4* __restrict__ Hs, const int* __restrict__ row_start,
    const int* __restrict__ csr_src, const float* __restrict__ norm_dst,
    __half* __restrict__ out) {
  int node = (blockIdx.x * 256 + threadIdx.x) >> 4;
  int lane = threadIdx.x & 15;
  if (node >= N_NODES) return;
  int s0 = row_start[node], s1 = row_start[node + 1];
  float a[8] = {0.f, 0.f, 0.f, 0.f, 0.f, 0.f, 0.f, 0.f};
  for (int e = s0; e < s1; e += 16) {
    int cnt = s1 - e;
    if (cnt > 16) cnt = 16;
    int idx = (lane < cnt) ? csr_src[e + lane] : 0;
    int j = 0;
    for (; j + 4 <= cnt; j += 4) {
      int i0 = __shfl(idx, j, 16);
      int i1 = __shfl(idx, j + 1, 16);
      int i2 = __shfl(idx, j + 2, 16);
      int i3 = __shfl(idx, j + 3, 16);
      float4 v0 = Hs[(size_t)i0 * 16 + lane];
      float4 v1 = Hs[(size_t)i1 * 16 + lane];
      float4 v2 = Hs[(size_t)i2 * 16 + lane];
      float4 v3 = Hs[(size_t)i3 * 16 + lane];
      acc8(a, v0);
      acc8(a, v1);
      acc8(a, v2);
      acc8(a, v3);
    }
    for (; j < cnt; ++j) {
      int i0 = __shfl(idx, j, 16);
      acc8(a, Hs[(size_t)i0 * 16 + lane]);
    }
  }
  float nd = norm_dst[node];
  union { __half2 h[4]; float4 f; } u;
  u.h[0] = __floats2half2_rn(a[0] * nd, a[1] * nd);
  u.h[1] = __floats2half2_rn(a[2] * nd, a[3] * nd);
  u.h[2] = __floats2half2_rn(a[4] * nd, a[5] * nd);
  u.h[3] = __floats2half2_rn(a[6] * nd, a[7] * nd);
  ((float4*)(out + (size_t)node * 128))[lane] = u.f;
}

// ---------------- readout ----------------
__global__ __launch_bounds__(256) void gbounds_k(const int* __restrict__ gid,
                                                 int* __restrict__ gstart) {
  int g = threadIdx.x;  // 0..128
  if (g > N_GRAPHS) return;
  int lo = 0, hi = N_NODES;
  while (lo < hi) {
    int mid = (lo + hi) >> 1;
    if (gid[mid] < g) lo = mid + 1; else hi = mid;
  }
  gstart[g] = lo;
}

__global__ __launch_bounds__(128) void gsum_k(const float* __restrict__ A,
                                              const int* __restrict__ gid,
                                              float* gsum) {
  int c = threadIdx.x;
  int n0 = blockIdx.x * 128;
  int n1 = n0 + 128;
  if (n1 > N_NODES) n1 = N_NODES;
  int cur = gid[n0];
  float local = 0.f;
  for (int n = n0; n < n1; ++n) {
    int g = gid[n];  // sorted: few changes per block
    if (g != cur) {
      atomicAdd(&gsum[cur * 128 + c], local);
      local = 0.f;
      cur = g;
    }
    local += A[(size_t)n * 128 + c];
  }
  atomicAdd(&gsum[cur * 128 + c], local);
}

__global__ __launch_bounds__(128) void gout_k(const float* __restrict__ gsum,
                                              const int* __restrict__ gstart,
                                              float* __restrict__ out) {
  int g = blockIdx.x, c = threadIdx.x;
  float cnt = (float)(gstart[g + 1] - gstart[g]);
  if (cnt < 1.f) cnt = 1.f;
  out[g * 128 + c] = gsum[g * 128 + c] / cnt;
}

// ---------------- launch ----------------
extern "C" void kernel_launch(void* const* d_in, const int* in_sizes, int n_in,
                              void* d_out, int out_size, void* d_ws,
                              size_t ws_size, hipStream_t stream) {
  const float* h = (const float*)d_in[0];
  const int* src = (const int*)d_in[1];
  const int* dst = (const int*)d_in[2];
  const int* gid = (const int*)d_in[3];
  const float* W_embed = (const float*)d_in[4];
  const float* b_embed = (const float*)d_in[5];
  const float* W_layers = (const float*)d_in[6];
  const float* b_layers = (const float*)d_in[7];
  const float* gamma = (const float*)d_in[8];
  const float* beta = (const float*)d_in[9];
  float* out = (float*)d_out;
  (void)in_sizes; (void)n_in; (void)out_size; (void)ws_size;

  char* ws = (char*)d_ws;
  size_t o = 0;
  auto alloc = [&](size_t bytes) -> char* {
    char* p = ws + o;
    o = (o + bytes + 255) & ~(size_t)255;
    return p;
  };
  float* norm_src = (float*)alloc(N_NODES * 4);
  float* norm_dst = (float*)alloc(N_NODES * 4);
  int* deg_out = (int*)alloc(N_NODES * 4);
  int* deg_in = (int*)alloc(N_NODES * 4);  // adjacent to deg_out (one memset)
  int* row_start = (int*)alloc((N_NODES + 1) * 4);
  int* bsums = (int*)alloc(SCAN_NB * 4);
  int* csr_src = (int*)alloc((size_t)N_EDGES * 4);
  int* rank = (int*)alloc((size_t)N_EDGES * 4);
  float* stats4 = (float*)alloc(N_LAYERS * 256 * 4);  // per-layer sum|sumsq
  float* gsum = (float*)alloc(N_GRAPHS * 128 * 4);    // adjacent to stats4
  int* gstart = (int*)alloc((N_GRAPHS + 1) * 4);
  float* sc_sh = (float*)alloc(256 * 4);
  __half* Bsw = (__half*)alloc(5 * 16384 * 2);  // swizzled W: embed + 4 layers
  float* A = (float*)alloc((size_t)N_NODES * 128 * 4);     // residual h (fp32)
  __half* P0h = (__half*)alloc((size_t)N_NODES * 128 * 2); // h*norm_src (fp16)
  __half* P1h = (__half*)alloc((size_t)N_NODES * 128 * 2); // agg (fp16)
  __half* H16 = (__half*)alloc((size_t)N_NODES * 128 * 2); // hl (fp16)

  // zero accumulators (deg_out+deg_in contiguous; stats4+gsum contiguous)
  hipMemsetAsync(deg_out, 0, 2 * 400128, stream);
  hipMemsetAsync(stats4, 0, 4096 + 65536, stream);

  degrank_k<<<(N_EDGES + 255) / 256, 256, 0, stream>>>(src, dst, deg_out,
                                                       deg_in, rank);
  norm_k<<<(N_NODES + 255) / 256, 256, 0, stream>>>(deg_out, deg_in, norm_src,
                                                    norm_dst);
  scan1_k<<<SCAN_NB, 256, 0, stream>>>(deg_in, bsums);
  scan2_k<<<1, 128, 0, stream>>>(bsums, row_start);
  scan3_k<<<SCAN_NB, 256, 0, stream>>>(deg_in, bsums, row_start);
  fill2_k<<<(N_EDGES + 255) / 256, 256, 0, stream>>>(src, dst, rank, row_start,
                                                     csr_src);

  wswz_k<<<8, 256, 0, stream>>>(W_embed, Bsw);
  wswz_k<<<32, 256, 0, stream>>>(W_layers, Bsw + 16384);

  // embed: A = h @ W_embed + b ; P0h = fp16(A * norm_src)
  mfma_gemm_f32in<<<(N_NODES + 127) / 128, 256, 0, stream>>>(
      h, Bsw, b_embed, A, P0h, norm_src);

  for (int l = 0; l < N_LAYERS; ++l) {
    gather_k<<<(N_NODES * 16 + 255) / 256, 256, 0, stream>>>(
        (const float4*)P0h, row_start, csr_src, norm_dst, P1h);
    mfma_gemm_f16<<<(N_NODES + 127) / 128, 256, 0, stream>>>(
        P1h, Bsw + (size_t)(1 + l) * 16384, b_layers + l * DIM, H16,
        stats4 + l * 256);
    bn_fin_k<<<1, 128, 0, stream>>>(stats4 + l * 256, gamma + l * DIM,
                                    beta + l * DIM, sc_sh);
    bnrelu_k<<<(N_NODES * 16 + 255) / 256, 256, 0, stream>>>(
        H16, A, P0h, sc_sh, norm_src, (l < N_LAYERS - 1) ? 1 : 0);
  }

  gbounds_k<<<1, 256, 0, stream>>>(gid, gstart);
  gsum_k<<<(N_NODES + 127) / 128, 128, 0, stream>>>(A, gid, gsum);
  gout_k<<<N_GRAPHS, 128, 0, stream>>>(gsum, gstart, out);
}

// Round 8
// 815.820 us; speedup vs baseline: 1.2219x; 1.1132x over previous
//
#include <hip/hip_runtime.h>
#include <hip/hip_bf16.h>
#include <hip/hip_fp16.h>

// GCN forward. fp16 storage for inter-layer tensors; fp32 accum everywhere
// (gather accum, MFMA accum, BN stats, residual, readout).
// R1: gcnt via binary search. R2: fp16 gather operand. R3: MFMA GEMM,
// pre-swizzled W. R4/R6: scattered-atomic CSR variants (124-235us).
// R7: radix-bucketed CSR build — bucket = node>>9 (196 buckets), LDS bucket
//     histograms + chunk claiming (writes land in per-block bucket chunks,
//     L2-combined), per-bucket 512-bin LDS histogram+scan gives coalesced
//     row_start/deg_out and L1-windowed csr fill. No 100K-bin scattered
//     atomics anywhere.

#define N_NODES 100000
#define N_EDGES 1600000
#define N_GRAPHS 128
#define DIM 128
#define N_LAYERS 4
#define BN_EPS 1e-5f
#define NBUCK 196          // ceil(N_NODES/512)
#define EPB 6250           // edges per block in bin/scatter passes (256 blocks)

typedef __attribute__((ext_vector_type(8))) _Float16 half8;
typedef __attribute__((ext_vector_type(4))) float floatx4;

// ---------------- pass A: bucket counts (LDS hist, 196 bins) ----------------
__global__ __launch_bounds__(256) void binA_k(const int* __restrict__ src,
                                              const int* __restrict__ dst,
                                              int* __restrict__ cnt_d,
                                              int* __restrict__ cnt_s) {
  __shared__ int hd[NBUCK], hs[NBUCK];
  int t = threadIdx.x;
  for (int i = t; i < NBUCK; i += 256) { hd[i] = 0; hs[i] = 0; }
  __syncthreads();
  int e0 = blockIdx.x * EPB;
  for (int e = e0 + t; e < e0 + EPB; e += 256) {
    atomicAdd(&hd[dst[e] >> 9], 1);
    atomicAdd(&hs[src[e] >> 9], 1);
  }
  __syncthreads();
  for (int i = t; i < NBUCK; i += 256) {
    if (hd[i]) atomicAdd(&cnt_d[i], hd[i]);
    if (hs[i]) atomicAdd(&cnt_s[i], hs[i]);
  }
}

// ---------------- scan of bucket counts -> bases + cursors ----------------
__global__ __launch_bounds__(256) void scan196_k(
    const int* __restrict__ cnt_d, const int* __restrict__ cnt_s,
    int* __restrict__ base_d, int* __restrict__ cur_d,
    int* __restrict__ base_s, int* __restrict__ cur_s,
    int* __restrict__ row_start) {
  __shared__ int sd[256], ss[256];
  int t = threadIdx.x;
  int vd = (t < NBUCK) ? cnt_d[t] : 0;
  int vs = (t < NBUCK) ? cnt_s[t] : 0;
  sd[t] = vd;
  ss[t] = vs;
  __syncthreads();
  for (int off = 1; off < 256; off <<= 1) {
    int ad = (t >= off) ? sd[t - off] : 0;
    int as = (t >= off) ? ss[t - off] : 0;
    __syncthreads();
    sd[t] += ad;
    ss[t] += as;
    __syncthreads();
  }
  if (t < NBUCK) {
    base_d[t] = sd[t] - vd;
    cur_d[t] = sd[t] - vd;
    base_s[t] = ss[t] - vs;
    cur_s[t] = ss[t] - vs;
  }
  if (t == 0) {
    base_d[NBUCK] = N_EDGES;
    base_s[NBUCK] = N_EDGES;
    row_start[N_NODES] = N_EDGES;
  }
}

// ---------------- pass B: scatter edges into bucket regions ----------------
// packed = (dst&511)<<17 | src  (src < 2^17). locs = src&511 (u16).
__global__ __launch_bounds__(256) void scat_k(
    const int* __restrict__ src, const int* __restrict__ dst,
    int* __restrict__ cur_d, int* __restrict__ cur_s,
    int* __restrict__ packed, unsigned short* __restrict__ locs) {
  __shared__ int hd[NBUCK], hs[NBUCK];
  int t = threadIdx.x;
  for (int i = t; i < NBUCK; i += 256) { hd[i] = 0; hs[i] = 0; }
  __syncthreads();
  int e0 = blockIdx.x * EPB;
  for (int e = e0 + t; e < e0 + EPB; e += 256) {
    atomicAdd(&hd[dst[e] >> 9], 1);
    atomicAdd(&hs[src[e] >> 9], 1);
  }
  __syncthreads();
  if (t < NBUCK) {  // claim chunks; hd/hs become running cursors
    hd[t] = atomicAdd(&cur_d[t], hd[t]);
    hs[t] = atomicAdd(&cur_s[t], hs[t]);
  }
  __syncthreads();
  for (int e = e0 + t; e < e0 + EPB; e += 256) {
    int s = src[e], d = dst[e];
    int slot = atomicAdd(&hd[d >> 9], 1);
    packed[slot] = ((d & 511) << 17) | s;
    int slot2 = atomicAdd(&hs[s >> 9], 1);
    locs[slot2] = (unsigned short)(s & 511);
  }
}

// ---------------- pass C (dst): per-bucket CSR: row_start + csr fill -------
__global__ __launch_bounds__(256) void cd_k(const int* __restrict__ base_d,
                                            const int* __restrict__ packed,
                                            int* __restrict__ row_start,
                                            int* __restrict__ csr_src) {
  __shared__ int sdeg[512], sinc[512], scur[512];
  int t = threadIdx.x;
  int b = blockIdx.x;
  int nbase = b << 9;
  int e0 = base_d[b], e1 = base_d[b + 1];
  sdeg[t] = 0;
  sdeg[t + 256] = 0;
  __syncthreads();
  for (int e = e0 + t; e < e1; e += 256) atomicAdd(&sdeg[packed[e] >> 17], 1);
  __syncthreads();
  sinc[t] = sdeg[t];
  sinc[t + 256] = sdeg[t + 256];
  __syncthreads();
  for (int off = 1; off < 512; off <<= 1) {
    int a0 = (t >= off) ? sinc[t - off] : 0;
    int i1 = t + 256;
    int a1 = (i1 >= off) ? sinc[i1 - off] : 0;
    __syncthreads();
    sinc[t] += a0;
    sinc[i1] += a1;
    __syncthreads();
  }
#pragma unroll
  for (int half = 0; half < 2; ++half) {
    int j = t + half * 256;
    int lofs = e0 + sinc[j] - sdeg[j];
    scur[j] = lofs;
    int node = nbase + j;
    if (node < N_NODES) row_start[node] = lofs;
  }
  __syncthreads();
  for (int e = e0 + t; e < e1; e += 256) {
    int p = packed[e];
    int slot = atomicAdd(&scur[p >> 17], 1);
    csr_src[slot] = p & 0x1FFFF;
  }
}

// ---------------- pass C (src): per-bucket histogram -> deg_out ------------
__global__ __launch_bounds__(256) void cs_k(const int* __restrict__ base_s,
                                            const unsigned short* __restrict__ locs,
                                            int* __restrict__ deg_out) {
  __shared__ int sdeg[512];
  int t = threadIdx.x;
  int b = blockIdx.x;
  int nbase = b << 9;
  int e0 = base_s[b], e1 = base_s[b + 1];
  sdeg[t] = 0;
  sdeg[t + 256] = 0;
  __syncthreads();
  for (int e = e0 + t; e < e1; e += 256) atomicAdd(&sdeg[locs[e]], 1);
  __syncthreads();
#pragma unroll
  for (int half = 0; half < 2; ++half) {
    int j = t + half * 256;
    int node = nbase + j;
    if (node < N_NODES) deg_out[node] = sdeg[j];
  }
}

// ---------------- norms (deg_in = row_start diff) ----------------
__global__ __launch_bounds__(256) void norm_k(const int* __restrict__ deg_out,
                                              const int* __restrict__ row_start,
                                              float* __restrict__ norm_src,
                                              float* __restrict__ norm_dst) {
  int i = blockIdx.x * 256 + threadIdx.x;
  if (i < N_NODES) {
    int din = row_start[i + 1] - row_start[i];
    int dso = deg_out[i] > 1 ? deg_out[i] : 1;
    int dsi = din > 1 ? din : 1;
    norm_src[i] = rsqrtf((float)dso);
    norm_dst[i] = rsqrtf((float)dsi);
  }
}

// ---------------- W pre-swizzle to B-fragment layout ----------------
__global__ __launch_bounds__(256) void wswz_k(const float* __restrict__ W,
                                              __half* __restrict__ Bsw) {
  int w = blockIdx.x >> 3, ct = blockIdx.x & 7;
  int ks = threadIdx.x >> 6, lane = threadIdx.x & 63;
  int n = ct * 16 + (lane & 15);
  int k0 = ks * 32 + (lane >> 4) * 8;
  const float* Wm = W + (size_t)w * 16384;
  __half* o = Bsw + ((((size_t)w * 8 + ct) * 4 + ks) * 64 + lane) * 8;
#pragma unroll
  for (int j = 0; j < 8; ++j) o[j] = __float2half(Wm[(k0 + j) * 128 + n]);
}

// ---------------- shared MFMA core (A-tile already in sA) ----------------
__device__ inline void mfma_core(const __half* sA, const __half* __restrict__ Bsw,
                                 floatx4 (&acc)[2][8], int w, int lane,
                                 int quad, int lrow) {
#pragma unroll
  for (int tr = 0; tr < 2; ++tr)
#pragma unroll
    for (int ct = 0; ct < 8; ++ct) acc[tr][ct] = (floatx4)(0.f);
#pragma unroll
  for (int ks = 0; ks < 4; ++ks) {
    half8 afrag[2];
#pragma unroll
    for (int tr = 0; tr < 2; ++tr) {
      int m = w * 32 + tr * 16 + lrow;
      afrag[tr] = *(const half8*)(&sA[m * 136 + ks * 32 + quad * 8]);
    }
#pragma unroll
    for (int ct = 0; ct < 8; ++ct) {
      half8 bfrag = *(const half8*)(&Bsw[(((size_t)ct * 4 + ks) * 64 + lane) * 8]);
      acc[0][ct] = __builtin_amdgcn_mfma_f32_16x16x32_f16(afrag[0], bfrag,
                                                          acc[0][ct], 0, 0, 0);
      acc[1][ct] = __builtin_amdgcn_mfma_f32_16x16x32_f16(afrag[1], bfrag,
                                                          acc[1][ct], 0, 0, 0);
    }
  }
}

// ---------------- embed GEMM: A = fp32 h @ W + b ; P0h = fp16(A*norm_src) ---
__global__ __launch_bounds__(256) void mfma_gemm_f32in(
    const float* __restrict__ X32, const __half* __restrict__ Bsw,
    const float* __restrict__ bias, float* __restrict__ Yf,
    __half* __restrict__ S16, const float* __restrict__ norm_src) {
  __shared__ __half sA[128 * 136];
  const int tid = threadIdx.x;
  const int w = tid >> 6, lane = tid & 63;
  const int quad = lane >> 4, lrow = lane & 15;
  const int row_base = blockIdx.x * 128;

#pragma unroll
  for (int i = 0; i < 16; ++i) {
    int g = i * 256 + tid;
    int r = g >> 5, q = g & 31;
    int row = row_base + r;
    float4 v = make_float4(0.f, 0.f, 0.f, 0.f);
    if (row < N_NODES) v = ((const float4*)X32)[(size_t)row * 32 + q];
    union { __half2 h[2]; float f[2]; } u;
    u.h[0] = __floats2half2_rn(v.x, v.y);
    u.h[1] = __floats2half2_rn(v.z, v.w);
    *(float2*)(&sA[r * 136 + q * 4]) = *(float2*)u.f;
  }
  __syncthreads();

  floatx4 acc[2][8];
  mfma_core(sA, Bsw, acc, w, lane, quad, lrow);

#pragma unroll
  for (int ct = 0; ct < 8; ++ct) {
    int col = ct * 16 + lrow;
    float b = bias[col];
#pragma unroll
    for (int tr = 0; tr < 2; ++tr)
#pragma unroll
      for (int reg = 0; reg < 4; ++reg) {
        int row = row_base + w * 32 + tr * 16 + quad * 4 + reg;
        if (row < N_NODES) {
          float y = acc[tr][ct][reg] + b;
          Yf[(size_t)row * 128 + col] = y;
          S16[(size_t)row * 128 + col] = __float2half(y * norm_src[row]);
        }
      }
  }
}

// ---------------- layer GEMM: hl16 = fp16( agg16 @ W + b ), + BN stats ----
__global__ __launch_bounds__(256) void mfma_gemm_f16(
    const __half* __restrict__ X16, const __half* __restrict__ Bsw,
    const float* __restrict__ bias, __half* __restrict__ hl16,
    float* __restrict__ stats) {
  __shared__ __half sA[128 * 136];
  const int tid = threadIdx.x;
  const int w = tid >> 6, lane = tid & 63;
  const int quad = lane >> 4, lrow = lane & 15;
  const int row_base = blockIdx.x * 128;

#pragma unroll
  for (int i = 0; i < 8; ++i) {
    int g = i * 256 + tid;
    int r = g >> 4, p = g & 15;
    int row = row_base + r;
    float4 v = make_float4(0.f, 0.f, 0.f, 0.f);
    if (row < N_NODES) v = ((const float4*)X16)[(size_t)row * 16 + p];
    *(float4*)(&sA[r * 136 + p * 8]) = v;
  }
  __syncthreads();

  floatx4 acc[2][8];
  mfma_core(sA, Bsw, acc, w, lane, quad, lrow);

  float psum[8], pqsum[8];
#pragma unroll
  for (int ct = 0; ct < 8; ++ct) {
    int col = ct * 16 + lrow;
    float b = bias[col];
    psum[ct] = 0.f;
    pqsum[ct] = 0.f;
#pragma unroll
    for (int tr = 0; tr < 2; ++tr)
#pragma unroll
      for (int reg = 0; reg < 4; ++reg) {
        int row = row_base + w * 32 + tr * 16 + quad * 4 + reg;
        if (row < N_NODES) {
          float y = acc[tr][ct][reg] + b;
          hl16[(size_t)row * 128 + col] = __float2half(y);
          psum[ct] += y;
          pqsum[ct] += y * y;
        }
      }
  }

#pragma unroll
  for (int ct = 0; ct < 8; ++ct) {
    psum[ct] += __shfl_xor(psum[ct], 16, 64);
    psum[ct] += __shfl_xor(psum[ct], 32, 64);
    pqsum[ct] += __shfl_xor(pqsum[ct], 16, 64);
    pqsum[ct] += __shfl_xor(pqsum[ct], 32, 64);
  }
  __syncthreads();
  float* sred = (float*)sA;
  if (quad == 0) {
#pragma unroll
    for (int ct = 0; ct < 8; ++ct) {
      sred[w * 128 + ct * 16 + lrow] = psum[ct];
      sred[512 + w * 128 + ct * 16 + lrow] = pqsum[ct];
    }
  }
  __syncthreads();
  if (tid < 128) {
    float s = sred[tid] + sred[128 + tid] + sred[256 + tid] + sred[384 + tid];
    float q = sred[512 + tid] + sred[640 + tid] + sred[768 + tid] +
              sred[896 + tid];
    atomicAdd(&stats[tid], s);
    atomicAdd(&stats[128 + tid], q);
  }
}

// ---------------- BN finalize ----------------
__global__ __launch_bounds__(128) void bn_fin_k(const float* __restrict__ stats,
                                                const float* __restrict__ gamma,
                                                const float* __restrict__ beta,
                                                float* __restrict__ sc_sh) {
  int c = threadIdx.x;
  const float invn = 1.0f / (float)N_NODES;
  float mean = stats[c] * invn;
  float var = stats[128 + c] * invn - mean * mean;
  var = fmaxf(var, 0.f);
  float sc = gamma[c] * rsqrtf(var + BN_EPS);
  sc_sh[c] = sc;
  sc_sh[128 + c] = beta[c] - mean * sc;
}

// ---------------- BN apply + ReLU + residual (+ fp16 scale for gather) -----
__global__ __launch_bounds__(256) void bnrelu_k(
    const __half* __restrict__ hl16, float* __restrict__ A,
    __half* __restrict__ S, const float* __restrict__ sc_sh,
    const float* __restrict__ norm_src, int write_scaled) {
  int idx = blockIdx.x * 256 + threadIdx.x;  // < N_NODES*16
  int node = idx >> 4;
  int c8 = idx & 15;
  float4 hv4 = *(const float4*)(hl16 + (size_t)idx * 8);
  const __half2* hp = (const __half2*)&hv4;
  const float4* sv = (const float4*)sc_sh;
  float4 s0 = sv[c8 * 2], s1 = sv[c8 * 2 + 1];
  float4 b0 = sv[32 + c8 * 2], b1 = sv[32 + c8 * 2 + 1];
  float4* Ap = (float4*)(A + (size_t)idx * 8);
  float4 a0 = Ap[0], a1 = Ap[1];
  float2 f0 = __half22float2(hp[0]), f1 = __half22float2(hp[1]);
  float2 f2 = __half22float2(hp[2]), f3 = __half22float2(hp[3]);
  float4 v0, v1;
  v0.x = fmaxf(f0.x * s0.x + b0.x, 0.f) + a0.x;
  v0.y = fmaxf(f0.y * s0.y + b0.y, 0.f) + a0.y;
  v0.z = fmaxf(f1.x * s0.z + b0.z, 0.f) + a0.z;
  v0.w = fmaxf(f1.y * s0.w + b0.w, 0.f) + a0.w;
  v1.x = fmaxf(f2.x * s1.x + b1.x, 0.f) + a1.x;
  v1.y = fmaxf(f2.y * s1.y + b1.y, 0.f) + a1.y;
  v1.z = fmaxf(f3.x * s1.z + b1.z, 0.f) + a1.z;
  v1.w = fmaxf(f3.y * s1.w + b1.w, 0.f) + a1.w;
  Ap[0] = v0;
  Ap[1] = v1;
  if (write_scaled) {
    float n = norm_src[node];
    union { __half2 h[4]; float4 f; } u;
    u.h[0] = __floats2half2_rn(v0.x * n, v0.y * n);
    u.h[1] = __floats2half2_rn(v0.z * n, v0.w * n);
    u.h[2] = __floats2half2_rn(v1.x * n, v1.y * n);
    u.h[3] = __floats2half2_rn(v1.z * n, v1.w * n);
    *(float4*)(S + (size_t)idx * 8) = u.f;
  }
}

// ---------------- pull aggregation (fp16 in, fp16 out, fp32 accum) ---------
__device__ inline void acc8(float (&a)[8], float4 v) {
  const __half2* hp = (const __half2*)&v;
#pragma unroll
  for (int q = 0; q < 4; ++q) {
    float2 f = __half22float2(hp[q]);
    a[2 * q] += f.x;
    a[2 * q + 1] += f.y;
  }
}

__global__ __launch_bounds__(256) void gather_k(
    const float4* __restrict__ Hs, const int* __restrict__ row_start,
    const int* __restrict__ csr_src, const float* __restrict__ norm_dst,
    __half* __restrict__ out) {
  int node = (blockIdx.x * 256 + threadIdx.x) >> 4;
  int lane = threadIdx.x & 15;
  if (node >= N_NODES) return;
  int s0 = row_start[node], s1 = row_start[node + 1];
  float a[8] = {0.f, 0.f, 0.f, 0.f, 0.f, 0.f, 0.f, 0.f};
  for (int e = s0; e < s1; e += 16) {
    int cnt = s1 - e;
    if (cnt > 16) cnt = 16;
    int idx = (lane < cnt) ? csr_src[e + lane] : 0;
    int j = 0;
    for (; j + 4 <= cnt; j += 4) {
      int i0 = __shfl(idx, j, 16);
      int i1 = __shfl(idx, j + 1, 16);
      int i2 = __shfl(idx, j + 2, 16);
      int i3 = __shfl(idx, j + 3, 16);
      float4 v0 = Hs[(size_t)i0 * 16 + lane];
      float4 v1 = Hs[(size_t)i1 * 16 + lane];
      float4 v2 = Hs[(size_t)i2 * 16 + lane];
      float4 v3 = Hs[(size_t)i3 * 16 + lane];
      acc8(a, v0);
      acc8(a, v1);
      acc8(a, v2);
      acc8(a, v3);
    }
    for (; j < cnt; ++j) {
      int i0 = __shfl(idx, j, 16);
      acc8(a, Hs[(size_t)i0 * 16 + lane]);
    }
  }
  float nd = norm_dst[node];
  union { __half2 h[4]; float4 f; } u;
  u.h[0] = __floats2half2_rn(a[0] * nd, a[1] * nd);
  u.h[1] = __floats2half2_rn(a[2] * nd, a[3] * nd);
  u.h[2] = __floats2half2_rn(a[4] * nd, a[5] * nd);
  u.h[3] = __floats2half2_rn(a[6] * nd, a[7] * nd);
  ((float4*)(out + (size_t)node * 128))[lane] = u.f;
}

// ---------------- readout ----------------
__global__ __launch_bounds__(256) void gbounds_k(const int* __restrict__ gid,
                                                 int* __restrict__ gstart) {
  int g = threadIdx.x;  // 0..128
  if (g > N_GRAPHS) return;
  int lo = 0, hi = N_NODES;
  while (lo < hi) {
    int mid = (lo + hi) >> 1;
    if (gid[mid] < g) lo = mid + 1; else hi = mid;
  }
  gstart[g] = lo;
}

__global__ __launch_bounds__(128) void gsum_k(const float* __restrict__ A,
                                              const int* __restrict__ gid,
                                              float* gsum) {
  int c = threadIdx.x;
  int n0 = blockIdx.x * 128;
  int n1 = n0 + 128;
  if (n1 > N_NODES) n1 = N_NODES;
  int cur = gid[n0];
  float local = 0.f;
  for (int n = n0; n < n1; ++n) {
    int g = gid[n];  // sorted: few changes per block
    if (g != cur) {
      atomicAdd(&gsum[cur * 128 + c], local);
      local = 0.f;
      cur = g;
    }
    local += A[(size_t)n * 128 + c];
  }
  atomicAdd(&gsum[cur * 128 + c], local);
}

__global__ __launch_bounds__(128) void gout_k(const float* __restrict__ gsum,
                                              const int* __restrict__ gstart,
                                              float* __restrict__ out) {
  int g = blockIdx.x, c = threadIdx.x;
  float cnt = (float)(gstart[g + 1] - gstart[g]);
  if (cnt < 1.f) cnt = 1.f;
  out[g * 128 + c] = gsum[g * 128 + c] / cnt;
}

// ---------------- launch ----------------
extern "C" void kernel_launch(void* const* d_in, const int* in_sizes, int n_in,
                              void* d_out, int out_size, void* d_ws,
                              size_t ws_size, hipStream_t stream) {
  const float* h = (const float*)d_in[0];
  const int* src = (const int*)d_in[1];
  const int* dst = (const int*)d_in[2];
  const int* gid = (const int*)d_in[3];
  const float* W_embed = (const float*)d_in[4];
  const float* b_embed = (const float*)d_in[5];
  const float* W_layers = (const float*)d_in[6];
  const float* b_layers = (const float*)d_in[7];
  const float* gamma = (const float*)d_in[8];
  const float* beta = (const float*)d_in[9];
  float* out = (float*)d_out;
  (void)in_sizes; (void)n_in; (void)out_size; (void)ws_size;

  char* ws = (char*)d_ws;
  size_t o = 0;
  auto alloc = [&](size_t bytes) -> char* {
    char* p = ws + o;
    o = (o + bytes + 255) & ~(size_t)255;
    return p;
  };
  int* cnt_d = (int*)alloc(NBUCK * 4);        // zeroed (one memset w/ cnt_s)
  int* cnt_s = (int*)alloc(NBUCK * 4);
  int* base_d = (int*)alloc((NBUCK + 1) * 4);
  int* cur_d = (int*)alloc(NBUCK * 4);
  int* base_s = (int*)alloc((NBUCK + 1) * 4);
  int* cur_s = (int*)alloc(NBUCK * 4);
  float* norm_src = (float*)alloc(N_NODES * 4);
  float* norm_dst = (float*)alloc(N_NODES * 4);
  int* deg_out = (int*)alloc(N_NODES * 4);
  int* row_start = (int*)alloc((N_NODES + 1) * 4);
  int* csr_src = (int*)alloc((size_t)N_EDGES * 4);
  int* packed = (int*)alloc((size_t)N_EDGES * 4);
  unsigned short* locs = (unsigned short*)alloc((size_t)N_EDGES * 2);
  float* stats4 = (float*)alloc(N_LAYERS * 256 * 4);  // per-layer sum|sumsq
  float* gsum = (float*)alloc(N_GRAPHS * 128 * 4);    // adjacent to stats4
  int* gstart = (int*)alloc((N_GRAPHS + 1) * 4);
  float* sc_sh = (float*)alloc(256 * 4);
  __half* Bsw = (__half*)alloc(5 * 16384 * 2);
  float* A = (float*)alloc((size_t)N_NODES * 128 * 4);     // residual h (fp32)
  __half* P0h = (__half*)alloc((size_t)N_NODES * 128 * 2); // h*norm_src (fp16)
  __half* P1h = (__half*)alloc((size_t)N_NODES * 128 * 2); // agg (fp16)
  __half* H16 = (__half*)alloc((size_t)N_NODES * 128 * 2); // hl (fp16)

  // zero bucket counters (cnt_d+cnt_s contiguous incl. padding) and stats
  hipMemsetAsync(cnt_d, 0, 2048, stream);
  hipMemsetAsync(stats4, 0, 4096 + 65536, stream);

  // ---- radix CSR build ----
  binA_k<<<256, 256, 0, stream>>>(src, dst, cnt_d, cnt_s);
  scan196_k<<<1, 256, 0, stream>>>(cnt_d, cnt_s, base_d, cur_d, base_s, cur_s,
                                   row_start);
  scat_k<<<256, 256, 0, stream>>>(src, dst, cur_d, cur_s, packed, locs);
  cd_k<<<NBUCK, 256, 0, stream>>>(base_d, packed, row_start, csr_src);
  cs_k<<<NBUCK, 256, 0, stream>>>(base_s, locs, deg_out);
  norm_k<<<(N_NODES + 255) / 256, 256, 0, stream>>>(deg_out, row_start,
                                                    norm_src, norm_dst);

  wswz_k<<<8, 256, 0, stream>>>(W_embed, Bsw);
  wswz_k<<<32, 256, 0, stream>>>(W_layers, Bsw + 16384);

  // embed: A = h @ W_embed + b ; P0h = fp16(A * norm_src)
  mfma_gemm_f32in<<<(N_NODES + 127) / 128, 256, 0, stream>>>(
      h, Bsw, b_embed, A, P0h, norm_src);

  for (int l = 0; l < N_LAYERS; ++l) {
    gather_k<<<(N_NODES * 16 + 255) / 256, 256, 0, stream>>>(
        (const float4*)P0h, row_start, csr_src, norm_dst, P1h);
    mfma_gemm_f16<<<(N_NODES + 127) / 128, 256, 0, stream>>>(
        P1h, Bsw + (size_t)(1 + l) * 16384, b_layers + l * DIM, H16,
        stats4 + l * 256);
    bn_fin_k<<<1, 128, 0, stream>>>(stats4 + l * 256, gamma + l * DIM,
                                    beta + l * DIM, sc_sh);
    bnrelu_k<<<(N_NODES * 16 + 255) / 256, 256, 0, stream>>>(
        H16, A, P0h, sc_sh, norm_src, (l < N_LAYERS - 1) ? 1 : 0);
  }

  gbounds_k<<<1, 256, 0, stream>>>(gid, gstart);
  gsum_k<<<(N_NODES + 127) / 128, 128, 0, stream>>>(A, gid, gsum);
  gout_k<<<N_GRAPHS, 128, 0, stream>>>(gsum, gstart, out);
}

// Round 9
// 783.853 us; speedup vs baseline: 1.2717x; 1.0408x over previous
//
#include <hip/hip_runtime.h>
#include <hip/hip_bf16.h>
#include <hip/hip_fp16.h>

// GCN forward. fp16 storage for ALL inter-layer tensors incl. residual;
// fp32 accum everywhere (gather accum, MFMA accum, BN stats, readout).
// R3: MFMA GEMM, pre-swizzled W. R7: radix-bucketed CSR build.
// R8: 64-row GEMM tiles (1563 blocks, 17.4KB LDS -> ~24 waves/CU, was 12);
//     fp16 residual A16 (embed/bnrelu/gsum traffic cut ~230MB); bn_fin fused
//     into bnrelu; gather 8-wide unrolled.

#define N_NODES 100000
#define N_EDGES 1600000
#define N_GRAPHS 128
#define DIM 128
#define N_LAYERS 4
#define BN_EPS 1e-5f
#define NBUCK 196          // ceil(N_NODES/512)
#define EPB 6250           // edges per block in bin/scatter passes (256 blocks)

typedef __attribute__((ext_vector_type(8))) _Float16 half8;
typedef __attribute__((ext_vector_type(4))) float floatx4;

// ---------------- pass A: bucket counts (LDS hist, 196 bins) ----------------
__global__ __launch_bounds__(256) void binA_k(const int* __restrict__ src,
                                              const int* __restrict__ dst,
                                              int* __restrict__ cnt_d,
                                              int* __restrict__ cnt_s) {
  __shared__ int hd[NBUCK], hs[NBUCK];
  int t = threadIdx.x;
  for (int i = t; i < NBUCK; i += 256) { hd[i] = 0; hs[i] = 0; }
  __syncthreads();
  int e0 = blockIdx.x * EPB;
  for (int e = e0 + t; e < e0 + EPB; e += 256) {
    atomicAdd(&hd[dst[e] >> 9], 1);
    atomicAdd(&hs[src[e] >> 9], 1);
  }
  __syncthreads();
  for (int i = t; i < NBUCK; i += 256) {
    if (hd[i]) atomicAdd(&cnt_d[i], hd[i]);
    if (hs[i]) atomicAdd(&cnt_s[i], hs[i]);
  }
}

// ---------------- scan of bucket counts -> bases + cursors ----------------
__global__ __launch_bounds__(256) void scan196_k(
    const int* __restrict__ cnt_d, const int* __restrict__ cnt_s,
    int* __restrict__ base_d, int* __restrict__ cur_d,
    int* __restrict__ base_s, int* __restrict__ cur_s,
    int* __restrict__ row_start) {
  __shared__ int sd[256], ss[256];
  int t = threadIdx.x;
  int vd = (t < NBUCK) ? cnt_d[t] : 0;
  int vs = (t < NBUCK) ? cnt_s[t] : 0;
  sd[t] = vd;
  ss[t] = vs;
  __syncthreads();
  for (int off = 1; off < 256; off <<= 1) {
    int ad = (t >= off) ? sd[t - off] : 0;
    int as = (t >= off) ? ss[t - off] : 0;
    __syncthreads();
    sd[t] += ad;
    ss[t] += as;
    __syncthreads();
  }
  if (t < NBUCK) {
    base_d[t] = sd[t] - vd;
    cur_d[t] = sd[t] - vd;
    base_s[t] = ss[t] - vs;
    cur_s[t] = ss[t] - vs;
  }
  if (t == 0) {
    base_d[NBUCK] = N_EDGES;
    base_s[NBUCK] = N_EDGES;
    row_start[N_NODES] = N_EDGES;
  }
}

// ---------------- pass B: scatter edges into bucket regions ----------------
// packed = (dst&511)<<17 | src  (src < 2^17). locs = src&511 (u16).
__global__ __launch_bounds__(256) void scat_k(
    const int* __restrict__ src, const int* __restrict__ dst,
    int* __restrict__ cur_d, int* __restrict__ cur_s,
    int* __restrict__ packed, unsigned short* __restrict__ locs) {
  __shared__ int hd[NBUCK], hs[NBUCK];
  int t = threadIdx.x;
  for (int i = t; i < NBUCK; i += 256) { hd[i] = 0; hs[i] = 0; }
  __syncthreads();
  int e0 = blockIdx.x * EPB;
  for (int e = e0 + t; e < e0 + EPB; e += 256) {
    atomicAdd(&hd[dst[e] >> 9], 1);
    atomicAdd(&hs[src[e] >> 9], 1);
  }
  __syncthreads();
  if (t < NBUCK) {  // claim chunks; hd/hs become running cursors
    hd[t] = atomicAdd(&cur_d[t], hd[t]);
    hs[t] = atomicAdd(&cur_s[t], hs[t]);
  }
  __syncthreads();
  for (int e = e0 + t; e < e0 + EPB; e += 256) {
    int s = src[e], d = dst[e];
    int slot = atomicAdd(&hd[d >> 9], 1);
    packed[slot] = ((d & 511) << 17) | s;
    int slot2 = atomicAdd(&hs[s >> 9], 1);
    locs[slot2] = (unsigned short)(s & 511);
  }
}

// ---------------- pass C (dst): per-bucket CSR: row_start + csr fill -------
__global__ __launch_bounds__(256) void cd_k(const int* __restrict__ base_d,
                                            const int* __restrict__ packed,
                                            int* __restrict__ row_start,
                                            int* __restrict__ csr_src) {
  __shared__ int sdeg[512], sinc[512], scur[512];
  int t = threadIdx.x;
  int b = blockIdx.x;
  int nbase = b << 9;
  int e0 = base_d[b], e1 = base_d[b + 1];
  sdeg[t] = 0;
  sdeg[t + 256] = 0;
  __syncthreads();
  for (int e = e0 + t; e < e1; e += 256) atomicAdd(&sdeg[packed[e] >> 17], 1);
  __syncthreads();
  sinc[t] = sdeg[t];
  sinc[t + 256] = sdeg[t + 256];
  __syncthreads();
  for (int off = 1; off < 512; off <<= 1) {
    int a0 = (t >= off) ? sinc[t - off] : 0;
    int i1 = t + 256;
    int a1 = (i1 >= off) ? sinc[i1 - off] : 0;
    __syncthreads();
    sinc[t] += a0;
    sinc[i1] += a1;
    __syncthreads();
  }
#pragma unroll
  for (int half = 0; half < 2; ++half) {
    int j = t + half * 256;
    int lofs = e0 + sinc[j] - sdeg[j];
    scur[j] = lofs;
    int node = nbase + j;
    if (node < N_NODES) row_start[node] = lofs;
  }
  __syncthreads();
  for (int e = e0 + t; e < e1; e += 256) {
    int p = packed[e];
    int slot = atomicAdd(&scur[p >> 17], 1);
    csr_src[slot] = p & 0x1FFFF;
  }
}

// ---------------- pass C (src): per-bucket histogram -> deg_out ------------
__global__ __launch_bounds__(256) void cs_k(const int* __restrict__ base_s,
                                            const unsigned short* __restrict__ locs,
                                            int* __restrict__ deg_out) {
  __shared__ int sdeg[512];
  int t = threadIdx.x;
  int b = blockIdx.x;
  int nbase = b << 9;
  int e0 = base_s[b], e1 = base_s[b + 1];
  sdeg[t] = 0;
  sdeg[t + 256] = 0;
  __syncthreads();
  for (int e = e0 + t; e < e1; e += 256) atomicAdd(&sdeg[locs[e]], 1);
  __syncthreads();
#pragma unroll
  for (int half = 0; half < 2; ++half) {
    int j = t + half * 256;
    int node = nbase + j;
    if (node < N_NODES) deg_out[node] = sdeg[j];
  }
}

// ---------------- norms (deg_in = row_start diff) ----------------
__global__ __launch_bounds__(256) void norm_k(const int* __restrict__ deg_out,
                                              const int* __restrict__ row_start,
                                              float* __restrict__ norm_src,
                                              float* __restrict__ norm_dst) {
  int i = blockIdx.x * 256 + threadIdx.x;
  if (i < N_NODES) {
    int din = row_start[i + 1] - row_start[i];
    int dso = deg_out[i] > 1 ? deg_out[i] : 1;
    int dsi = din > 1 ? din : 1;
    norm_src[i] = rsqrtf((float)dso);
    norm_dst[i] = rsqrtf((float)dsi);
  }
}

// ---------------- W pre-swizzle to B-fragment layout ----------------
__global__ __launch_bounds__(256) void wswz_k(const float* __restrict__ W,
                                              __half* __restrict__ Bsw) {
  int w = blockIdx.x >> 3, ct = blockIdx.x & 7;
  int ks = threadIdx.x >> 6, lane = threadIdx.x & 63;
  int n = ct * 16 + (lane & 15);
  int k0 = ks * 32 + (lane >> 4) * 8;
  const float* Wm = W + (size_t)w * 16384;
  __half* o = Bsw + ((((size_t)w * 8 + ct) * 4 + ks) * 64 + lane) * 8;
#pragma unroll
  for (int j = 0; j < 8; ++j) o[j] = __float2half(Wm[(k0 + j) * 128 + n]);
}

// ---------------- MFMA core: wave w computes 16 rows x 128 cols ----------
// C layout per 16x16 tile: row = quad*4 + reg, col = ct*16 + lrow.
__device__ inline void mfma_core16(const __half* sA,
                                   const __half* __restrict__ Bsw,
                                   floatx4 (&acc)[8], int w, int lane,
                                   int quad, int lrow) {
#pragma unroll
  for (int ct = 0; ct < 8; ++ct) acc[ct] = (floatx4)(0.f);
#pragma unroll
  for (int ks = 0; ks < 4; ++ks) {
    int m = w * 16 + lrow;
    half8 afrag = *(const half8*)(&sA[m * 136 + ks * 32 + quad * 8]);
#pragma unroll
    for (int ct = 0; ct < 8; ++ct) {
      half8 bfrag = *(const half8*)(&Bsw[(((size_t)ct * 4 + ks) * 64 + lane) * 8]);
      acc[ct] = __builtin_amdgcn_mfma_f32_16x16x32_f16(afrag, bfrag, acc[ct],
                                                       0, 0, 0);
    }
  }
}

// ---------------- embed GEMM: A16 = fp16(h @ W + b); P0h = fp16(.*ns) ------
// 64-row tile, 256 thr = 4 waves, wave w: rows [w*16, w*16+16).
__global__ __launch_bounds__(256) void mfma_gemm_f32in(
    const float* __restrict__ X32, const __half* __restrict__ Bsw,
    const float* __restrict__ bias, __half* __restrict__ A16,
    __half* __restrict__ S16, const float* __restrict__ norm_src) {
  __shared__ __half sA[64 * 136];  // 17.4 KB
  const int tid = threadIdx.x;
  const int w = tid >> 6, lane = tid & 63;
  const int quad = lane >> 4, lrow = lane & 15;
  const int row_base = blockIdx.x * 64;

  // stage fp32 tile -> fp16 LDS (2048 float4 reads)
#pragma unroll
  for (int i = 0; i < 8; ++i) {
    int g = i * 256 + tid;
    int r = g >> 5, q = g & 31;
    int row = row_base + r;
    float4 v = make_float4(0.f, 0.f, 0.f, 0.f);
    if (row < N_NODES) v = ((const float4*)X32)[(size_t)row * 32 + q];
    union { __half2 h[2]; float f[2]; } u;
    u.h[0] = __floats2half2_rn(v.x, v.y);
    u.h[1] = __floats2half2_rn(v.z, v.w);
    *(float2*)(&sA[r * 136 + q * 4]) = *(float2*)u.f;
  }
  __syncthreads();

  floatx4 acc[8];
  mfma_core16(sA, Bsw, acc, w, lane, quad, lrow);

#pragma unroll
  for (int ct = 0; ct < 8; ++ct) {
    int col = ct * 16 + lrow;
    float b = bias[col];
#pragma unroll
    for (int reg = 0; reg < 4; ++reg) {
      int row = row_base + w * 16 + quad * 4 + reg;
      if (row < N_NODES) {
        float y = acc[ct][reg] + b;
        A16[(size_t)row * 128 + col] = __float2half(y);
        S16[(size_t)row * 128 + col] = __float2half(y * norm_src[row]);
      }
    }
  }
}

// ---------------- layer GEMM: hl16 = fp16(agg16 @ W + b), + BN stats ------
__global__ __launch_bounds__(256) void mfma_gemm_f16(
    const __half* __restrict__ X16, const __half* __restrict__ Bsw,
    const float* __restrict__ bias, __half* __restrict__ hl16,
    float* __restrict__ stats) {
  __shared__ __half sA[64 * 136];
  const int tid = threadIdx.x;
  const int w = tid >> 6, lane = tid & 63;
  const int quad = lane >> 4, lrow = lane & 15;
  const int row_base = blockIdx.x * 64;

  // stage fp16 tile (1024 float4 reads)
#pragma unroll
  for (int i = 0; i < 4; ++i) {
    int g = i * 256 + tid;
    int r = g >> 4, p = g & 15;
    int row = row_base + r;
    float4 v = make_float4(0.f, 0.f, 0.f, 0.f);
    if (row < N_NODES) v = ((const float4*)X16)[(size_t)row * 16 + p];
    *(float4*)(&sA[r * 136 + p * 8]) = v;
  }
  __syncthreads();

  floatx4 acc[8];
  mfma_core16(sA, Bsw, acc, w, lane, quad, lrow);

  float psum[8], pqsum[8];
#pragma unroll
  for (int ct = 0; ct < 8; ++ct) {
    int col = ct * 16 + lrow;
    float b = bias[col];
    psum[ct] = 0.f;
    pqsum[ct] = 0.f;
#pragma unroll
    for (int reg = 0; reg < 4; ++reg) {
      int row = row_base + w * 16 + quad * 4 + reg;
      if (row < N_NODES) {
        float y = acc[ct][reg] + b;
        hl16[(size_t)row * 128 + col] = __float2half(y);
        psum[ct] += y;
        pqsum[ct] += y * y;
      }
    }
  }

#pragma unroll
  for (int ct = 0; ct < 8; ++ct) {
    psum[ct] += __shfl_xor(psum[ct], 16, 64);
    psum[ct] += __shfl_xor(psum[ct], 32, 64);
    pqsum[ct] += __shfl_xor(pqsum[ct], 16, 64);
    pqsum[ct] += __shfl_xor(pqsum[ct], 32, 64);
  }
  __syncthreads();
  float* sred = (float*)sA;  // [4 waves][128] sum | [4][128] sumsq
  if (quad == 0) {
#pragma unroll
    for (int ct = 0; ct < 8; ++ct) {
      sred[w * 128 + ct * 16 + lrow] = psum[ct];
      sred[512 + w * 128 + ct * 16 + lrow] = pqsum[ct];
    }
  }
  __syncthreads();
  if (tid < 128) {
    float s = sred[tid] + sred[128 + tid] + sred[256 + tid] + sred[384 + tid];
    float q = sred[512 + tid] + sred[640 + tid] + sred[768 + tid] +
              sred[896 + tid];
    atomicAdd(&stats[tid], s);
    atomicAdd(&stats[128 + tid], q);
  }
}

// ---------------- BN apply + ReLU + residual (bn_fin fused) ----------------
// Block first computes the 128 scale/shift pairs from stats in LDS.
__global__ __launch_bounds__(256) void bnrelu_k(
    const __half* __restrict__ hl16, __half* __restrict__ A16,
    __half* __restrict__ S, const float* __restrict__ stats,
    const float* __restrict__ gamma, const float* __restrict__ beta,
    const float* __restrict__ norm_src, int write_scaled) {
  __shared__ float ssc[128], ssh[128];
  int t = threadIdx.x;
  if (t < 128) {
    const float invn = 1.0f / (float)N_NODES;
    float mean = stats[t] * invn;
    float var = stats[128 + t] * invn - mean * mean;
    var = fmaxf(var, 0.f);
    float sc = gamma[t] * rsqrtf(var + BN_EPS);
    ssc[t] = sc;
    ssh[t] = beta[t] - mean * sc;
  }
  __syncthreads();
  int idx = blockIdx.x * 256 + t;  // < N_NODES*16
  int node = idx >> 4;
  int c0 = (idx & 15) * 8;
  float4 hv4 = *(const float4*)(hl16 + (size_t)idx * 8);
  float4 av4 = *(const float4*)(A16 + (size_t)idx * 8);
  const __half2* hp = (const __half2*)&hv4;
  const __half2* ap = (const __half2*)&av4;
  float n = write_scaled ? norm_src[node] : 0.f;
  float v[8];
#pragma unroll
  for (int q = 0; q < 4; ++q) {
    float2 f = __half22float2(hp[q]);
    float2 a = __half22float2(ap[q]);
    v[2 * q] = fmaxf(f.x * ssc[c0 + 2 * q] + ssh[c0 + 2 * q], 0.f) + a.x;
    v[2 * q + 1] =
        fmaxf(f.y * ssc[c0 + 2 * q + 1] + ssh[c0 + 2 * q + 1], 0.f) + a.y;
  }
  union { __half2 h[4]; float4 f; } ua;
#pragma unroll
  for (int q = 0; q < 4; ++q)
    ua.h[q] = __floats2half2_rn(v[2 * q], v[2 * q + 1]);
  *(float4*)(A16 + (size_t)idx * 8) = ua.f;
  if (write_scaled) {
    union { __half2 h[4]; float4 f; } us;
#pragma unroll
    for (int q = 0; q < 4; ++q)
      us.h[q] = __floats2half2_rn(v[2 * q] * n, v[2 * q + 1] * n);
    *(float4*)(S + (size_t)idx * 8) = us.f;
  }
}

// ---------------- pull aggregation (fp16 in, fp16 out, fp32 accum) ---------
__device__ inline void acc8(float (&a)[8], float4 v) {
  const __half2* hp = (const __half2*)&v;
#pragma unroll
  for (int q = 0; q < 4; ++q) {
    float2 f = __half22float2(hp[q]);
    a[2 * q] += f.x;
    a[2 * q + 1] += f.y;
  }
}

__global__ __launch_bounds__(256) void gather_k(
    const float4* __restrict__ Hs, const int* __restrict__ row_start,
    const int* __restrict__ csr_src, const float* __restrict__ norm_dst,
    __half* __restrict__ out) {
  int node = (blockIdx.x * 256 + threadIdx.x) >> 4;
  int lane = threadIdx.x & 15;
  if (node >= N_NODES) return;
  int s0 = row_start[node], s1 = row_start[node + 1];
  float a[8] = {0.f, 0.f, 0.f, 0.f, 0.f, 0.f, 0.f, 0.f};
  for (int e = s0; e < s1; e += 16) {
    int cnt = s1 - e;
    if (cnt > 16) cnt = 16;
    int idx = (lane < cnt) ? csr_src[e + lane] : 0;
    int j = 0;
    for (; j + 8 <= cnt; j += 8) {
      int i0 = __shfl(idx, j, 16);
      int i1 = __shfl(idx, j + 1, 16);
      int i2 = __shfl(idx, j + 2, 16);
      int i3 = __shfl(idx, j + 3, 16);
      int i4 = __shfl(idx, j + 4, 16);
      int i5 = __shfl(idx, j + 5, 16);
      int i6 = __shfl(idx, j + 6, 16);
      int i7 = __shfl(idx, j + 7, 16);
      float4 v0 = Hs[(size_t)i0 * 16 + lane];
      float4 v1 = Hs[(size_t)i1 * 16 + lane];
      float4 v2 = Hs[(size_t)i2 * 16 + lane];
      float4 v3 = Hs[(size_t)i3 * 16 + lane];
      float4 v4 = Hs[(size_t)i4 * 16 + lane];
      float4 v5 = Hs[(size_t)i5 * 16 + lane];
      float4 v6 = Hs[(size_t)i6 * 16 + lane];
      float4 v7 = Hs[(size_t)i7 * 16 + lane];
      acc8(a, v0); acc8(a, v1); acc8(a, v2); acc8(a, v3);
      acc8(a, v4); acc8(a, v5); acc8(a, v6); acc8(a, v7);
    }
    for (; j + 4 <= cnt; j += 4) {
      int i0 = __shfl(idx, j, 16);
      int i1 = __shfl(idx, j + 1, 16);
      int i2 = __shfl(idx, j + 2, 16);
      int i3 = __shfl(idx, j + 3, 16);
      float4 v0 = Hs[(size_t)i0 * 16 + lane];
      float4 v1 = Hs[(size_t)i1 * 16 + lane];
      float4 v2 = Hs[(size_t)i2 * 16 + lane];
      float4 v3 = Hs[(size_t)i3 * 16 + lane];
      acc8(a, v0); acc8(a, v1); acc8(a, v2); acc8(a, v3);
    }
    for (; j < cnt; ++j) {
      int i0 = __shfl(idx, j, 16);
      acc8(a, Hs[(size_t)i0 * 16 + lane]);
    }
  }
  float nd = norm_dst[node];
  union { __half2 h[4]; float4 f; } u;
  u.h[0] = __floats2half2_rn(a[0] * nd, a[1] * nd);
  u.h[1] = __floats2half2_rn(a[2] * nd, a[3] * nd);
  u.h[2] = __floats2half2_rn(a[4] * nd, a[5] * nd);
  u.h[3] = __floats2half2_rn(a[6] * nd, a[7] * nd);
  ((float4*)(out + (size_t)node * 128))[lane] = u.f;
}

// ---------------- readout ----------------
__global__ __launch_bounds__(256) void gbounds_k(const int* __restrict__ gid,
                                                 int* __restrict__ gstart) {
  int g = threadIdx.x;  // 0..128
  if (g > N_GRAPHS) return;
  int lo = 0, hi = N_NODES;
  while (lo < hi) {
    int mid = (lo + hi) >> 1;
    if (gid[mid] < g) lo = mid + 1; else hi = mid;
  }
  gstart[g] = lo;
}

__global__ __launch_bounds__(128) void gsum_k(const __half* __restrict__ A16,
                                              const int* __restrict__ gid,
                                              float* gsum) {
  int c = threadIdx.x;
  int n0 = blockIdx.x * 128;
  int n1 = n0 + 128;
  if (n1 > N_NODES) n1 = N_NODES;
  int cur = gid[n0];
  float local = 0.f;
  for (int n = n0; n < n1; ++n) {
    int g = gid[n];  // sorted: few changes per block
    if (g != cur) {
      atomicAdd(&gsum[cur * 128 + c], local);
      local = 0.f;
      cur = g;
    }
    local += __half2float(A16[(size_t)n * 128 + c]);
  }
  atomicAdd(&gsum[cur * 128 + c], local);
}

__global__ __launch_bounds__(128) void gout_k(const float* __restrict__ gsum,
                                              const int* __restrict__ gstart,
                                              float* __restrict__ out) {
  int g = blockIdx.x, c = threadIdx.x;
  float cnt = (float)(gstart[g + 1] - gstart[g]);
  if (cnt < 1.f) cnt = 1.f;
  out[g * 128 + c] = gsum[g * 128 + c] / cnt;
}

// ---------------- launch ----------------
extern "C" void kernel_launch(void* const* d_in, const int* in_sizes, int n_in,
                              void* d_out, int out_size, void* d_ws,
                              size_t ws_size, hipStream_t stream) {
  const float* h = (const float*)d_in[0];
  const int* src = (const int*)d_in[1];
  const int* dst = (const int*)d_in[2];
  const int* gid = (const int*)d_in[3];
  const float* W_embed = (const float*)d_in[4];
  const float* b_embed = (const float*)d_in[5];
  const float* W_layers = (const float*)d_in[6];
  const float* b_layers = (const float*)d_in[7];
  const float* gamma = (const float*)d_in[8];
  const float* beta = (const float*)d_in[9];
  float* out = (float*)d_out;
  (void)in_sizes; (void)n_in; (void)out_size; (void)ws_size;

  char* ws = (char*)d_ws;
  size_t o = 0;
  auto alloc = [&](size_t bytes) -> char* {
    char* p = ws + o;
    o = (o + bytes + 255) & ~(size_t)255;
    return p;
  };
  int* cnt_d = (int*)alloc(NBUCK * 4);  // zeroed (one memset w/ cnt_s)
  int* cnt_s = (int*)alloc(NBUCK * 4);
  int* base_d = (int*)alloc((NBUCK + 1) * 4);
  int* cur_d = (int*)alloc(NBUCK * 4);
  int* base_s = (int*)alloc((NBUCK + 1) * 4);
  int* cur_s = (int*)alloc(NBUCK * 4);
  float* norm_src = (float*)alloc(N_NODES * 4);
  float* norm_dst = (float*)alloc(N_NODES * 4);
  int* deg_out = (int*)alloc(N_NODES * 4);
  int* row_start = (int*)alloc((N_NODES + 1) * 4);
  int* csr_src = (int*)alloc((size_t)N_EDGES * 4);
  int* packed = (int*)alloc((size_t)N_EDGES * 4);
  unsigned short* locs = (unsigned short*)alloc((size_t)N_EDGES * 2);
  float* stats4 = (float*)alloc(N_LAYERS * 256 * 4);  // per-layer sum|sumsq
  float* gsum = (float*)alloc(N_GRAPHS * 128 * 4);    // adjacent to stats4
  int* gstart = (int*)alloc((N_GRAPHS + 1) * 4);
  __half* Bsw = (__half*)alloc(5 * 16384 * 2);
  __half* A16 = (__half*)alloc((size_t)N_NODES * 128 * 2);  // residual (fp16)
  __half* P0h = (__half*)alloc((size_t)N_NODES * 128 * 2);  // h*ns (fp16)
  __half* P1h = (__half*)alloc((size_t)N_NODES * 128 * 2);  // agg (fp16)
  __half* H16 = (__half*)alloc((size_t)N_NODES * 128 * 2);  // hl (fp16)

  // zero bucket counters and stats (+gsum, contiguous)
  hipMemsetAsync(cnt_d, 0, 2048, stream);
  hipMemsetAsync(stats4, 0, 4096 + 65536, stream);

  // ---- radix CSR build ----
  binA_k<<<256, 256, 0, stream>>>(src, dst, cnt_d, cnt_s);
  scan196_k<<<1, 256, 0, stream>>>(cnt_d, cnt_s, base_d, cur_d, base_s, cur_s,
                                   row_start);
  scat_k<<<256, 256, 0, stream>>>(src, dst, cur_d, cur_s, packed, locs);
  cd_k<<<NBUCK, 256, 0, stream>>>(base_d, packed, row_start, csr_src);
  cs_k<<<NBUCK, 256, 0, stream>>>(base_s, locs, deg_out);
  norm_k<<<(N_NODES + 255) / 256, 256, 0, stream>>>(deg_out, row_start,
                                                    norm_src, norm_dst);

  wswz_k<<<8, 256, 0, stream>>>(W_embed, Bsw);
  wswz_k<<<32, 256, 0, stream>>>(W_layers, Bsw + 16384);

  // embed: A16 = fp16(h @ W_embed + b) ; P0h = fp16(. * norm_src)
  mfma_gemm_f32in<<<(N_NODES + 63) / 64, 256, 0, stream>>>(
      h, Bsw, b_embed, A16, P0h, norm_src);

  for (int l = 0; l < N_LAYERS; ++l) {
    gather_k<<<(N_NODES * 16 + 255) / 256, 256, 0, stream>>>(
        (const float4*)P0h, row_start, csr_src, norm_dst, P1h);
    mfma_gemm_f16<<<(N_NODES + 63) / 64, 256, 0, stream>>>(
        P1h, Bsw + (size_t)(1 + l) * 16384, b_layers + l * DIM, H16,
        stats4 + l * 256);
    bnrelu_k<<<(N_NODES * 16 + 255) / 256, 256, 0, stream>>>(
        H16, A16, P0h, stats4 + l * 256, gamma + l * DIM, beta + l * DIM,
        norm_src, (l < N_LAYERS - 1) ? 1 : 0);
  }

  gbounds_k<<<1, 256, 0, stream>>>(gid, gstart);
  gsum_k<<<(N_NODES + 127) / 128, 128, 0, stream>>>(A16, gid, gsum);
  gout_k<<<N_GRAPHS, 128, 0, stream>>>(gsum, gstart, out);
}